// Round 1
// baseline (2327.717 us; speedup 1.0000x reference)
//
#include <hip/hip_runtime.h>
#include <math.h>

#define NN 200000
#define EEDGE 500000
#define BB 4096
#define KK 20
#define MM 100000
#define Q3 (3*BB)

__device__ __forceinline__ float dot4(float4 a, float4 b) {
    return a.x*b.x + a.y*b.y + a.z*b.z + a.w*b.w;
}

// time encoding matching numpy rounding: cos(round(round(dt*w)+b)) — NO fma
// contraction (args can be ~5e6 where fma-vs-mul+add shifts arg by ~0.25).
__device__ __forceinline__ float tenc(float dt, float w, float b) {
    float p = __fmul_rn(dt, w);
    float a = __fadd_rn(p, b);
    return cosf(a);
}

__global__ void k_init(int* lastpos, int* inv, int* count) {
    int i = blockIdx.x * 256 + threadIdx.x;
    if (i < NN) { lastpos[i] = -1; inv[i] = -1; }
    if (i == 0) *count = 0;
}

__global__ void k_scatter(const int* __restrict__ msg_src, int* __restrict__ lastpos) {
    int i = blockIdx.x * 256 + threadIdx.x;
    if (i < MM) atomicMax(&lastpos[msg_src[i]], i);
}

__global__ void k_compact(const int* __restrict__ lastpos, int* __restrict__ inv,
                          int* __restrict__ comp, int* __restrict__ count) {
    int n = blockIdx.x * 256 + threadIdx.x;
    if (n < NN && lastpos[n] >= 0) {
        int j = atomicAdd(count, 1);
        comp[j] = n;
        inv[n] = j;
    }
}

// Stage 1: per 16 compacted msg-nodes: raw(512) -> relu GEMM(256) -> GEMM(128)
// -> GRU gates (2x 128->384) fused in-register -> new_mem[slot][128].
__global__ void k_stage1(const int* __restrict__ comp, const int* __restrict__ count,
                         const int* __restrict__ lastpos,
                         const int* __restrict__ msg_dst, const int* __restrict__ msg_eidx,
                         const int* __restrict__ msg_t, const int* __restrict__ last_update,
                         const float* __restrict__ memory, const float* __restrict__ edge_feats,
                         const float* __restrict__ time_w, const float* __restrict__ time_b,
                         const float* __restrict__ W1, const float* __restrict__ b1,
                         const float* __restrict__ W2, const float* __restrict__ b2,
                         const float* __restrict__ Wi, const float* __restrict__ Wh,
                         const float* __restrict__ bi, const float* __restrict__ bh,
                         float* __restrict__ new_mem)
{
    __shared__ float raw[16][512];   // [memory[n] | memory[d] | edge | time] per row
    __shared__ float h1s[16][256];
    __shared__ float msgs[16][128];
    __shared__ int sn[16], sd[16], se[16];
    __shared__ float sdt[16];

    int cnt = *count;
    int r0 = blockIdx.x * 16;
    if (r0 >= cnt) return;
    int tid = threadIdx.x;

    if (tid < 16) {
        int rr = r0 + tid;
        int j = (rr < cnt) ? rr : r0;   // clamp (dup row, writes guarded later)
        int n = comp[j];
        int idx = lastpos[n];           // >= 0 for compacted nodes; msg_src[idx] == n
        sn[tid] = n;
        sd[tid] = msg_dst[idx];
        se[tid] = msg_eidx[idx];
        sdt[tid] = (float)(msg_t[idx] - last_update[n]);
    }
    __syncthreads();

    // build raw[16][512]
    for (int x = tid; x < 16 * 512; x += 256) {
        int r = x >> 9, c = x & 511;
        float v;
        if (c < 128)      v = memory[(size_t)sn[r] * 128 + c];
        else if (c < 256) v = memory[(size_t)sd[r] * 128 + (c - 128)];
        else if (c < 384) v = edge_feats[(size_t)se[r] * 128 + (c - 256)];
        else              v = tenc(sdt[r], time_w[c - 384], time_b[c - 384]);
        raw[r][c] = v;
    }
    __syncthreads();

    // GEMM1: h1[16][256] = relu(raw @ W1^T + b1); thread = (half, 2 cols)
    {
        int half = tid >> 7;
        int c0 = (tid & 127) * 2;
        int rb = half * 8;
        float a0[8], a1[8];
        #pragma unroll
        for (int r = 0; r < 8; r++) { a0[r] = 0.f; a1[r] = 0.f; }
        const float4* w0 = (const float4*)(W1 + (size_t)c0 * 512);
        const float4* w1 = (const float4*)(W1 + (size_t)(c0 + 1) * 512);
        for (int k4 = 0; k4 < 128; k4++) {
            float4 wa = w0[k4], wb = w1[k4];
            #pragma unroll
            for (int r = 0; r < 8; r++) {
                float4 av = *((const float4*)&raw[rb + r][k4 * 4]);
                a0[r] += dot4(av, wa);
                a1[r] += dot4(av, wb);
            }
        }
        float bb0 = b1[c0], bb1 = b1[c0 + 1];
        #pragma unroll
        for (int r = 0; r < 8; r++) {
            h1s[rb + r][c0]     = fmaxf(a0[r] + bb0, 0.f);
            h1s[rb + r][c0 + 1] = fmaxf(a1[r] + bb1, 0.f);
        }
    }
    __syncthreads();

    // GEMM2: msg[16][128] = h1 @ W2^T + b2
    {
        int half = tid >> 7;
        int c = tid & 127;
        int rb = half * 8;
        float acc[8];
        #pragma unroll
        for (int r = 0; r < 8; r++) acc[r] = 0.f;
        const float4* w = (const float4*)(W2 + (size_t)c * 256);
        for (int k4 = 0; k4 < 64; k4++) {
            float4 wv = w[k4];
            #pragma unroll
            for (int r = 0; r < 8; r++) {
                float4 av = *((const float4*)&h1s[rb + r][k4 * 4]);
                acc[r] += dot4(av, wv);
            }
        }
        float bb = b2[c];
        #pragma unroll
        for (int r = 0; r < 8; r++) msgs[rb + r][c] = acc[r] + bb;
    }
    __syncthreads();

    // GEMM3 (msg@Wi^T) + GEMM4 (mem@Wh^T) for gate cols (c, c+128, c+256) + GRU
    {
        int half = tid >> 7;
        int c = tid & 127;
        int rb = half * 8;
        float ar[8], az[8], an_[8], ah[8];
        #pragma unroll
        for (int r = 0; r < 8; r++) { ar[r] = 0.f; az[r] = 0.f; an_[r] = 0.f; ah[r] = 0.f; }
        {
            const float4* wr = (const float4*)(Wi + (size_t)c * 128);
            const float4* wz = (const float4*)(Wi + (size_t)(128 + c) * 128);
            const float4* wn = (const float4*)(Wi + (size_t)(256 + c) * 128);
            for (int k4 = 0; k4 < 32; k4++) {
                float4 w_r = wr[k4], w_z = wz[k4], w_n = wn[k4];
                #pragma unroll
                for (int r = 0; r < 8; r++) {
                    float4 av = *((const float4*)&msgs[rb + r][k4 * 4]);
                    ar[r]  += dot4(av, w_r);
                    az[r]  += dot4(av, w_z);
                    an_[r] += dot4(av, w_n);
                }
            }
        }
        {
            const float4* wr = (const float4*)(Wh + (size_t)c * 128);
            const float4* wz = (const float4*)(Wh + (size_t)(128 + c) * 128);
            const float4* wn = (const float4*)(Wh + (size_t)(256 + c) * 128);
            for (int k4 = 0; k4 < 32; k4++) {
                float4 w_r = wr[k4], w_z = wz[k4], w_n = wn[k4];
                #pragma unroll
                for (int r = 0; r < 8; r++) {
                    float4 av = *((const float4*)&raw[rb + r][k4 * 4]);  // memory[n]
                    ar[r] += dot4(av, w_r);
                    az[r] += dot4(av, w_z);
                    ah[r] += dot4(av, w_n);
                }
            }
        }
        float brz = bi[c] + bh[c];
        float bzz = bi[128 + c] + bh[128 + c];
        float bin_ = bi[256 + c];
        float bhn_ = bh[256 + c];
        #pragma unroll
        for (int r = 0; r < 8; r++) {
            int rr = r0 + rb + r;
            if (rr < cnt) {
                float rg = 1.f / (1.f + expf(-(ar[r] + brz)));
                float zg = 1.f / (1.f + expf(-(az[r] + bzz)));
                float nn = tanhf(an_[r] + bin_ + rg * (ah[r] + bhn_));
                float om = raw[rb + r][c];
                new_mem[(size_t)rr * 128 + c] = (1.f - zg) * nn + zg * om;
            }
        }
    }
}

// Stage 2: 8 queries per block. q -> qk=Wk_h^T q (folds K GEMM), online-softmax
// over 20 neighbors with register wsum, ctx = Wv wsum + bv, Wo, merge MLP.
__global__ void k_stage2(const int* __restrict__ src_nodes, const int* __restrict__ dst_nodes,
                         const int* __restrict__ neg_nodes, const int* __restrict__ edge_times,
                         const int* __restrict__ neighbors, const int* __restrict__ nb_eidx,
                         const int* __restrict__ nb_et,
                         const int* __restrict__ inv, const float* __restrict__ new_mem,
                         const float* __restrict__ memory, const float* __restrict__ node_feats,
                         const float* __restrict__ edge_feats,
                         const float* __restrict__ time_w, const float* __restrict__ time_b,
                         const float* __restrict__ Wq, const float* __restrict__ bq,
                         const float* __restrict__ Wk, const float* __restrict__ bk,
                         const float* __restrict__ Wv, const float* __restrict__ bv,
                         const float* __restrict__ Wo, const float* __restrict__ bo,
                         const float* __restrict__ mW1, const float* __restrict__ mb1,
                         const float* __restrict__ mW2, const float* __restrict__ mb2,
                         float* __restrict__ out)
{
    __shared__ float sfeat[8][128];    // src_feat
    __shared__ float buf256[8][256];   // q_in -> ctx
    __shared__ float buf256b[8][256];  // q -> attn_out
    __shared__ float qk[8][768];       // qk -> wsum
    __shared__ float kin[8][384];      // per-neighbor k_in -> merge hidden
    __shared__ float tss[8];
    __shared__ int nodeid[8];
    __shared__ int allm[8];

    int tid = threadIdx.x;
    int q0 = blockIdx.x * 8;

    if (tid < 8) {
        int q = q0 + tid;
        int node = (q < BB) ? src_nodes[q] : (q < 2 * BB) ? dst_nodes[q - BB] : neg_nodes[q - 2 * BB];
        nodeid[tid] = node;
        tss[tid] = (float)edge_times[q & (BB - 1)];
        int am = 1;
        for (int j = 0; j < KK; j++) if (neighbors[(size_t)q * KK + j] != 0) am = 0;
        allm[tid] = am;
    }
    __syncthreads();

    // P0: src_feat and q_in (time_enc(0) = cos(time_b))
    for (int x = tid; x < 8 * 128; x += 256) {
        int b = x >> 7, c = x & 127;
        int n = nodeid[b];
        int iv = inv[n];
        float mv = (iv >= 0) ? new_mem[(size_t)iv * 128 + c] : memory[(size_t)n * 128 + c];
        float sf = mv + node_feats[(size_t)n * 128 + c];
        sfeat[b][c] = sf;
        buf256[b][c] = sf;
        buf256[b][128 + c] = cosf(time_b[c]);
    }
    __syncthreads();

    // P1: q = q_in @ Wq^T + bq
    {
        int c = tid;
        float acc[8];
        float bb = bq[c];
        #pragma unroll
        for (int b = 0; b < 8; b++) acc[b] = bb;
        const float4* w = (const float4*)(Wq + (size_t)c * 256);
        for (int k4 = 0; k4 < 64; k4++) {
            float4 wv = w[k4];
            #pragma unroll
            for (int b = 0; b < 8; b++) {
                float4 av = *((const float4*)&buf256[b][k4 * 4]);
                acc[b] += dot4(av, wv);
            }
        }
        #pragma unroll
        for (int b = 0; b < 8; b++) buf256b[b][c] = acc[b];
    }
    __syncthreads();

    // group (b,h) per 16 lanes; cb = q_h . bk_h (replicated across group lanes)
    int lane = tid & 15;
    int gb = tid >> 5;          // query in block
    int gh = (tid >> 4) & 1;    // head
    float cb = 0.f;
    #pragma unroll
    for (int i = 0; i < 8; i++) {
        int e = lane + 16 * i;
        cb += buf256b[gb][gh * 128 + e] * bk[gh * 128 + e];
    }
    cb += __shfl_xor(cb, 1, 16);
    cb += __shfl_xor(cb, 2, 16);
    cb += __shfl_xor(cb, 4, 16);
    cb += __shfl_xor(cb, 8, 16);

    // P2: qk[b][h*384+j] = sum_c q[b][h*128+c] * Wk[h*128+c][j]
    {
        float qa[3][8];
        #pragma unroll
        for (int s = 0; s < 3; s++)
            #pragma unroll
            for (int b = 0; b < 8; b++) qa[s][b] = 0.f;
        #pragma unroll
        for (int s = 0; s < 3; s++) {
            int hj = tid + s * 256;
            int h = hj / 384, j = hj % 384;
            const float* wcol = Wk + (size_t)h * 128 * 384 + j;
            for (int c4 = 0; c4 < 32; c4++) {
                float w0 = wcol[(size_t)(c4 * 4 + 0) * 384];
                float w1 = wcol[(size_t)(c4 * 4 + 1) * 384];
                float w2 = wcol[(size_t)(c4 * 4 + 2) * 384];
                float w3 = wcol[(size_t)(c4 * 4 + 3) * 384];
                #pragma unroll
                for (int b = 0; b < 8; b++) {
                    float4 qv = *((const float4*)&buf256b[b][h * 128 + c4 * 4]);
                    qa[s][b] += qv.x * w0 + qv.y * w1 + qv.z * w2 + qv.w * w3;
                }
            }
        }
        #pragma unroll
        for (int s = 0; s < 3; s++) {
            int hj = tid + s * 256;
            #pragma unroll
            for (int b = 0; b < 8; b++) qk[b][hj] = qa[s][b];
        }
    }
    __syncthreads();

    // P3: neighbor loop with online softmax; wacc = running sum of p * k_in
    float m_run = -3.0e38f, l_run = 0.f;
    float wacc[24];
    #pragma unroll
    for (int i = 0; i < 24; i++) wacc[i] = 0.f;
    int b2 = tid >> 5, l32 = tid & 31;
    const float inv_sqrt = 0.08838834764831845f;   // 1/sqrt(128)

    for (int j = 0; j < KK; j++) {
        {
            int row = q0 + b2;
            int nb = neighbors[(size_t)row * KK + j];
            int eidx = nb_eidx[(size_t)row * KK + j];
            float dtf = tss[b2] - (float)nb_et[(size_t)row * KK + j];
            int iv = inv[nb];
            #pragma unroll
            for (int i = 0; i < 4; i++) {
                int c = l32 + 32 * i;
                float mv = (iv >= 0) ? new_mem[(size_t)iv * 128 + c] : memory[(size_t)nb * 128 + c];
                kin[b2][c] = mv + node_feats[(size_t)nb * 128 + c];
            }
            #pragma unroll
            for (int i = 0; i < 4; i++) {
                int c = l32 + 32 * i;
                kin[b2][128 + c] = tenc(dtf, time_w[c], time_b[c]);
            }
            #pragma unroll
            for (int i = 0; i < 4; i++) {
                int c = l32 + 32 * i;
                kin[b2][256 + c] = edge_feats[(size_t)eidx * 128 + c];
            }
        }
        __syncthreads();

        float part = 0.f;
        #pragma unroll
        for (int i = 0; i < 24; i++) {
            int e = lane + 16 * i;
            part += qk[gb][gh * 384 + e] * kin[gb][e];
        }
        part += __shfl_xor(part, 1, 16);
        part += __shfl_xor(part, 2, 16);
        part += __shfl_xor(part, 4, 16);
        part += __shfl_xor(part, 8, 16);
        float s = (part + cb) * inv_sqrt;
        int nbq = neighbors[(size_t)(q0 + gb) * KK + j];
        if (nbq == 0) s = -1e9f;
        float m_new = fmaxf(m_run, s);
        float scale = expf(m_run - m_new);
        float p = expf(s - m_new);
        l_run = l_run * scale + p;
        #pragma unroll
        for (int i = 0; i < 24; i++) {
            wacc[i] = wacc[i] * scale + p * kin[gb][lane + 16 * i];
        }
        m_run = m_new;
        __syncthreads();
    }
    // wsum into qk region (qk dead now)
    {
        float linv = 1.f / l_run;
        #pragma unroll
        for (int i = 0; i < 24; i++) qk[gb][gh * 384 + lane + 16 * i] = wacc[i] * linv;
    }
    __syncthreads();

    // P4: ctx[b][h*128+c] = bv + Wv[h*128+c][:] . wsum[b][h]
    {
        int h = tid >> 7;
        float acc[8];
        float bb = bv[tid];
        #pragma unroll
        for (int b = 0; b < 8; b++) acc[b] = bb;
        const float4* w = (const float4*)(Wv + (size_t)tid * 384);
        for (int k4 = 0; k4 < 96; k4++) {
            float4 wv = w[k4];
            #pragma unroll
            for (int b = 0; b < 8; b++) {
                float4 av = *((const float4*)&qk[b][h * 384 + k4 * 4]);
                acc[b] += dot4(av, wv);
            }
        }
        #pragma unroll
        for (int b = 0; b < 8; b++) buf256[b][tid] = acc[b];  // ctx (reuse)
    }
    __syncthreads();

    // P5: attn_out = ctx @ Wo^T + bo; zero if all neighbors padded
    {
        int c = tid;
        float acc[8];
        float bb = bo[c];
        #pragma unroll
        for (int b = 0; b < 8; b++) acc[b] = bb;
        const float4* w = (const float4*)(Wo + (size_t)c * 256);
        for (int k4 = 0; k4 < 64; k4++) {
            float4 wv = w[k4];
            #pragma unroll
            for (int b = 0; b < 8; b++) {
                float4 av = *((const float4*)&buf256[b][k4 * 4]);
                acc[b] += dot4(av, wv);
            }
        }
        #pragma unroll
        for (int b = 0; b < 8; b++) buf256b[b][c] = allm[b] ? 0.f : acc[b];
    }
    __syncthreads();

    // P6: merge hidden = relu([attn_out, src_feat] @ mW1^T + mb1)
    float* hm = &kin[0][0];   // reuse (8*128 floats)
    {
        int half = tid >> 7, c = tid & 127;
        float acc[4];
        float bb = mb1[c];
        #pragma unroll
        for (int r = 0; r < 4; r++) acc[r] = bb;
        const float4* w = (const float4*)(mW1 + (size_t)c * 384);
        for (int k4 = 0; k4 < 64; k4++) {
            float4 wv = w[k4];
            #pragma unroll
            for (int r = 0; r < 4; r++) {
                float4 av = *((const float4*)&buf256b[half * 4 + r][k4 * 4]);
                acc[r] += dot4(av, wv);
            }
        }
        for (int k4 = 64; k4 < 96; k4++) {
            float4 wv = w[k4];
            #pragma unroll
            for (int r = 0; r < 4; r++) {
                float4 av = *((const float4*)&sfeat[half * 4 + r][(k4 - 64) * 4]);
                acc[r] += dot4(av, wv);
            }
        }
        #pragma unroll
        for (int r = 0; r < 4; r++) hm[(half * 4 + r) * 128 + c] = fmaxf(acc[r], 0.f);
    }
    __syncthreads();

    // P7: emb = hm @ mW2^T + mb2 -> out
    {
        int half = tid >> 7, c = tid & 127;
        float acc[4];
        float bb = mb2[c];
        #pragma unroll
        for (int r = 0; r < 4; r++) acc[r] = bb;
        const float4* w = (const float4*)(mW2 + (size_t)c * 128);
        for (int k4 = 0; k4 < 32; k4++) {
            float4 wv = w[k4];
            #pragma unroll
            for (int r = 0; r < 4; r++) {
                float4 av = *((const float4*)&hm[(half * 4 + r) * 128 + k4 * 4]);
                acc[r] += dot4(av, wv);
            }
        }
        #pragma unroll
        for (int r = 0; r < 4; r++)
            out[(size_t)(q0 + half * 4 + r) * 128 + c] = acc[r];
    }
}

extern "C" void kernel_launch(void* const* d_in, const int* in_sizes, int n_in,
                              void* d_out, int out_size, void* d_ws, size_t ws_size,
                              hipStream_t stream) {
    (void)in_sizes; (void)n_in; (void)out_size; (void)ws_size;
    const int* src_nodes  = (const int*)d_in[0];
    const int* dst_nodes  = (const int*)d_in[1];
    const int* neg_nodes  = (const int*)d_in[2];
    const int* edge_times = (const int*)d_in[3];
    const int* neighbors  = (const int*)d_in[4];
    const int* nb_eidx    = (const int*)d_in[5];
    const int* nb_et      = (const int*)d_in[6];
    const int* msg_src    = (const int*)d_in[7];
    const int* msg_dst    = (const int*)d_in[8];
    const int* msg_eidx   = (const int*)d_in[9];
    const int* msg_t      = (const int*)d_in[10];
    const int* last_update= (const int*)d_in[11];
    const float* node_feats = (const float*)d_in[12];
    const float* edge_feats = (const float*)d_in[13];
    const float* memory     = (const float*)d_in[14];
    const float* time_w = (const float*)d_in[15];
    const float* time_b = (const float*)d_in[16];
    const float* W1 = (const float*)d_in[17];
    const float* b1 = (const float*)d_in[18];
    const float* W2 = (const float*)d_in[19];
    const float* b2 = (const float*)d_in[20];
    const float* gWi = (const float*)d_in[21];
    const float* gWh = (const float*)d_in[22];
    const float* gbi = (const float*)d_in[23];
    const float* gbh = (const float*)d_in[24];
    const float* Wq = (const float*)d_in[25];
    const float* bq = (const float*)d_in[26];
    const float* Wk = (const float*)d_in[27];
    const float* bk = (const float*)d_in[28];
    const float* Wv = (const float*)d_in[29];
    const float* bv = (const float*)d_in[30];
    const float* Wo = (const float*)d_in[31];
    const float* bo = (const float*)d_in[32];
    const float* mW1 = (const float*)d_in[33];
    const float* mb1 = (const float*)d_in[34];
    const float* mW2 = (const float*)d_in[35];
    const float* mb2 = (const float*)d_in[36];
    float* out = (float*)d_out;

    char* w = (char*)d_ws;
    int* lastpos = (int*)w;
    int* inv  = lastpos + NN;
    int* comp = inv + NN;
    int* count = comp + NN;
    size_t off = ((size_t)(3 * NN + 1) * 4 + 255) & ~(size_t)255;
    float* new_mem = (float*)(w + off);   // up to MM*128 floats (51.2 MB)

    k_init<<<dim3((NN + 255) / 256), dim3(256), 0, stream>>>(lastpos, inv, count);
    k_scatter<<<dim3((MM + 255) / 256), dim3(256), 0, stream>>>(msg_src, lastpos);
    k_compact<<<dim3((NN + 255) / 256), dim3(256), 0, stream>>>(lastpos, inv, comp, count);
    k_stage1<<<dim3(MM / 16), dim3(256), 0, stream>>>(
        comp, count, lastpos, msg_dst, msg_eidx, msg_t, last_update,
        memory, edge_feats, time_w, time_b,
        W1, b1, W2, b2, gWi, gWh, gbi, gbh, new_mem);
    k_stage2<<<dim3(Q3 / 8), dim3(256), 0, stream>>>(
        src_nodes, dst_nodes, neg_nodes, edge_times, neighbors, nb_eidx, nb_et,
        inv, new_mem, memory, node_feats, edge_feats, time_w, time_b,
        Wq, bq, Wk, bk, Wv, bv, Wo, bo, mW1, mb1, mW2, mb2, out);
}

// Round 2
// 856.602 us; speedup vs baseline: 2.7174x; 2.7174x over previous
//
#include <hip/hip_runtime.h>
#include <math.h>

#define NN 200000
#define EEDGE 500000
#define BB 4096
#define KK 20
#define MM 100000
#define Q3 (3*BB)

typedef _Float16 __attribute__((ext_vector_type(8))) f16x8;
typedef _Float16 __attribute__((ext_vector_type(4))) f16x4;
typedef float __attribute__((ext_vector_type(4))) f32x4;

#define MFMA16(a,b,c) __builtin_amdgcn_mfma_f32_16x16x32_f16(a,b,c,0,0,0)

__device__ __forceinline__ float dot4(float4 a, float4 b) {
    return a.x*b.x + a.y*b.y + a.z*b.z + a.w*b.w;
}

// time encoding matching numpy rounding — NO fma contraction (args ~5e6).
__device__ __forceinline__ float tenc(float dt, float w, float b) {
    float p = __fmul_rn(dt, w);
    float a = __fadd_rn(p, b);
    return cosf(a);
}

// swizzled byte address into the 32x1024B stage-1 LDS tile (G4 XOR swizzle)
__device__ __forceinline__ int SWA(int r, int byteofs) {
    return r * 1024 + (byteofs ^ ((r & 7) << 4));
}

__device__ __forceinline__ f32x4 z4() {
    f32x4 v; v[0] = 0.f; v[1] = 0.f; v[2] = 0.f; v[3] = 0.f; return v;
}

__global__ void k_init(int* lastpos, int* inv, int* count) {
    int i = blockIdx.x * 256 + threadIdx.x;
    if (i < NN) { lastpos[i] = -1; inv[i] = -1; }
    if (i == 0) *count = 0;
}

__global__ void k_scatter(const int* __restrict__ msg_src, int* __restrict__ lastpos) {
    int i = blockIdx.x * 256 + threadIdx.x;
    if (i < MM) atomicMax(&lastpos[msg_src[i]], i);
}

__global__ void k_compact(const int* __restrict__ lastpos, int* __restrict__ inv,
                          int* __restrict__ comp, int* __restrict__ count) {
    int n = blockIdx.x * 256 + threadIdx.x;
    if (n < NN && lastpos[n] >= 0) {
        int j = atomicAdd(count, 1);
        comp[j] = n;
        inv[n] = j;
    }
}

// convert stage-1 weights f32 -> f16 once per call
__global__ void k_cvtw(const float* __restrict__ W1, const float* __restrict__ W2,
                       const float* __restrict__ Wi, const float* __restrict__ Wh,
                       _Float16* __restrict__ W1h, _Float16* __restrict__ W2h,
                       _Float16* __restrict__ Wih, _Float16* __restrict__ Whh) {
    int i = (blockIdx.x * 256 + threadIdx.x) * 4;
    const float* src; _Float16* dst; int o;
    if (i < 131072)      { src = W1; dst = W1h; o = i; }
    else if (i < 163840) { src = W2; dst = W2h; o = i - 131072; }
    else if (i < 212992) { src = Wi; dst = Wih; o = i - 163840; }
    else                 { src = Wh; dst = Whh; o = i - 212992; }
    float4 v = *(const float4*)(src + o);
    f16x4 h; h[0] = (_Float16)v.x; h[1] = (_Float16)v.y; h[2] = (_Float16)v.z; h[3] = (_Float16)v.w;
    *(f16x4*)(dst + o) = h;
}

// Stage 1 (MFMA f16): 32 msg-nodes per block, 4 waves.
// LDS row (1024B): [0..255] mem[n] f16 | [256..383] free | [384..895] h1 (later msg) | tail free
// raw occupies full row during GEMM1 (mem[n] | mem[d] | edge | time-enc).
__global__ __launch_bounds__(256, 3)
void k_stage1(const int* __restrict__ comp, const int* __restrict__ count,
              const int* __restrict__ lastpos,
              const int* __restrict__ msg_dst, const int* __restrict__ msg_eidx,
              const int* __restrict__ msg_t, const int* __restrict__ last_update,
              const float* __restrict__ memory, const float* __restrict__ edge_feats,
              const float* __restrict__ time_w, const float* __restrict__ time_b,
              const _Float16* __restrict__ W1h, const float* __restrict__ b1,
              const _Float16* __restrict__ W2h, const float* __restrict__ b2,
              const _Float16* __restrict__ Wih, const _Float16* __restrict__ Whh,
              const float* __restrict__ bi, const float* __restrict__ bh,
              float* __restrict__ new_mem)
{
    __shared__ char rawb[32 * 1024];
    __shared__ int sn[32], sd[32], se[32];
    __shared__ float sdt[32];

    int cnt = *count;
    int r0 = blockIdx.x * 32;
    if (r0 >= cnt) return;
    int tid = threadIdx.x;

    if (tid < 32) {
        int rr = r0 + tid;
        int j = (rr < cnt) ? rr : r0;       // clamp: dup row, writes guarded
        int n = comp[j];
        int idx = lastpos[n];
        sn[tid] = n;
        sd[tid] = msg_dst[idx];
        se[tid] = msg_eidx[idx];
        sdt[tid] = (float)(msg_t[idx] - last_update[n]);
    }
    __syncthreads();

    // ---- build raw[32][512] as f16 (swizzled), 8B-granule per thread x8 ----
    #pragma unroll
    for (int t = 0; t < 8; t++) {
        int gi = tid + t * 256;
        int r = gi >> 6, g = gi & 63;      // granule g: cols g*8..g*8+7
        char* dst = rawb + SWA(r, g * 16);
        f16x8 h;
        if (g < 48) {
            const float* src;
            if (g < 16)      src = memory + (size_t)sn[r] * 128 + g * 8;
            else if (g < 32) src = memory + (size_t)sd[r] * 128 + (g - 16) * 8;
            else             src = edge_feats + (size_t)se[r] * 128 + (g - 32) * 8;
            float4 a = *(const float4*)src;
            float4 b = *(const float4*)(src + 4);
            h[0] = (_Float16)a.x; h[1] = (_Float16)a.y; h[2] = (_Float16)a.z; h[3] = (_Float16)a.w;
            h[4] = (_Float16)b.x; h[5] = (_Float16)b.y; h[6] = (_Float16)b.z; h[7] = (_Float16)b.w;
        } else {
            int c = (g - 48) * 8;
            float4 w0 = *(const float4*)(time_w + c);
            float4 w1 = *(const float4*)(time_w + c + 4);
            float4 t0 = *(const float4*)(time_b + c);
            float4 t1 = *(const float4*)(time_b + c + 4);
            float dt = sdt[r];
            h[0] = (_Float16)tenc(dt, w0.x, t0.x); h[1] = (_Float16)tenc(dt, w0.y, t0.y);
            h[2] = (_Float16)tenc(dt, w0.z, t0.z); h[3] = (_Float16)tenc(dt, w0.w, t0.w);
            h[4] = (_Float16)tenc(dt, w1.x, t1.x); h[5] = (_Float16)tenc(dt, w1.y, t1.y);
            h[6] = (_Float16)tenc(dt, w1.z, t1.z); h[7] = (_Float16)tenc(dt, w1.w, t1.w);
        }
        *(f16x8*)dst = h;
    }
    __syncthreads();

    int wv = tid >> 6, lane = tid & 63;
    int arow = lane & 15, kg = lane >> 4;   // kg in 0..3

    // ---- GEMM1: h1[32][256] = relu(raw @ W1^T + b1), K=512 ----
    f32x4 acc1[4][2];
    #pragma unroll
    for (int c = 0; c < 4; c++) { acc1[c][0] = z4(); acc1[c][1] = z4(); }
    for (int ks = 0; ks < 16; ks++) {
        f16x8 a0 = *(const f16x8*)(rawb + SWA(arow,      ks * 64 + kg * 16));
        f16x8 a1 = *(const f16x8*)(rawb + SWA(16 + arow, ks * 64 + kg * 16));
        #pragma unroll
        for (int c = 0; c < 4; c++) {
            int col = (wv * 4 + c) * 16 + arow;
            f16x8 b = *(const f16x8*)(W1h + (size_t)col * 512 + ks * 32 + kg * 8);
            acc1[c][0] = MFMA16(a0, b, acc1[c][0]);
            acc1[c][1] = MFMA16(a1, b, acc1[c][1]);
        }
    }
    __syncthreads();   // all reads of raw row done before h1 overlay

    #pragma unroll
    for (int c = 0; c < 4; c++) {
        int col = (wv * 4 + c) * 16 + arow;
        float bb = b1[col];
        #pragma unroll
        for (int rt = 0; rt < 2; rt++)
            #pragma unroll
            for (int rg = 0; rg < 4; rg++) {
                int row = rt * 16 + kg * 4 + rg;
                float v = acc1[c][rt][rg] + bb;
                v = fmaxf(v, 0.f);
                *(_Float16*)(rawb + SWA(row, 384 + col * 2)) = (_Float16)v;
            }
    }
    __syncthreads();

    // ---- GEMM2: msg[32][128] = h1 @ W2^T + b2, K=256 ----
    f32x4 acc2[2][2];
    #pragma unroll
    for (int c = 0; c < 2; c++) { acc2[c][0] = z4(); acc2[c][1] = z4(); }
    for (int ks = 0; ks < 8; ks++) {
        f16x8 a0 = *(const f16x8*)(rawb + SWA(arow,      384 + ks * 64 + kg * 16));
        f16x8 a1 = *(const f16x8*)(rawb + SWA(16 + arow, 384 + ks * 64 + kg * 16));
        #pragma unroll
        for (int c = 0; c < 2; c++) {
            int col = (wv * 2 + c) * 16 + arow;
            f16x8 b = *(const f16x8*)(W2h + (size_t)col * 256 + ks * 32 + kg * 8);
            acc2[c][0] = MFMA16(a0, b, acc2[c][0]);
            acc2[c][1] = MFMA16(a1, b, acc2[c][1]);
        }
    }
    __syncthreads();   // h1 reads done; overlay msg onto h1's first half

    #pragma unroll
    for (int c = 0; c < 2; c++) {
        int col = (wv * 2 + c) * 16 + arow;
        float bb = b2[col];
        #pragma unroll
        for (int rt = 0; rt < 2; rt++)
            #pragma unroll
            for (int rg = 0; rg < 4; rg++) {
                int row = rt * 16 + kg * 4 + rg;
                *(_Float16*)(rawb + SWA(row, 384 + col * 2)) =
                    (_Float16)(acc2[c][rt][rg] + bb);
            }
    }
    __syncthreads();

    // ---- GEMM3/4 + GRU: gates over msg (K=128) and mem (K=128) ----
    f32x4 aR[2][2], aZ[2][2], aNi[2][2], aNh[2][2];
    #pragma unroll
    for (int c = 0; c < 2; c++)
        #pragma unroll
        for (int rt = 0; rt < 2; rt++) {
            aR[c][rt] = z4(); aZ[c][rt] = z4(); aNi[c][rt] = z4(); aNh[c][rt] = z4();
        }
    for (int ks = 0; ks < 4; ks++) {
        f16x8 m0 = *(const f16x8*)(rawb + SWA(arow,      384 + ks * 64 + kg * 16));
        f16x8 m1 = *(const f16x8*)(rawb + SWA(16 + arow, 384 + ks * 64 + kg * 16));
        f16x8 h0 = *(const f16x8*)(rawb + SWA(arow,      ks * 64 + kg * 16));
        f16x8 h1v = *(const f16x8*)(rawb + SWA(16 + arow, ks * 64 + kg * 16));
        #pragma unroll
        for (int c = 0; c < 2; c++) {
            int col = (wv * 2 + c) * 16 + arow;
            const _Float16* pi = Wih + (size_t)col * 128 + ks * 32 + kg * 8;
            const _Float16* ph = Whh + (size_t)col * 128 + ks * 32 + kg * 8;
            f16x8 bri = *(const f16x8*)pi;
            f16x8 bzi = *(const f16x8*)(pi + 128 * 128);
            f16x8 bni = *(const f16x8*)(pi + 256 * 128);
            f16x8 brh = *(const f16x8*)ph;
            f16x8 bzh = *(const f16x8*)(ph + 128 * 128);
            f16x8 bnh = *(const f16x8*)(ph + 256 * 128);
            aR[c][0] = MFMA16(m0, bri, aR[c][0]);  aR[c][0] = MFMA16(h0, brh, aR[c][0]);
            aR[c][1] = MFMA16(m1, bri, aR[c][1]);  aR[c][1] = MFMA16(h1v, brh, aR[c][1]);
            aZ[c][0] = MFMA16(m0, bzi, aZ[c][0]);  aZ[c][0] = MFMA16(h0, bzh, aZ[c][0]);
            aZ[c][1] = MFMA16(m1, bzi, aZ[c][1]);  aZ[c][1] = MFMA16(h1v, bzh, aZ[c][1]);
            aNi[c][0] = MFMA16(m0, bni, aNi[c][0]);
            aNi[c][1] = MFMA16(m1, bni, aNi[c][1]);
            aNh[c][0] = MFMA16(h0, bnh, aNh[c][0]);
            aNh[c][1] = MFMA16(h1v, bnh, aNh[c][1]);
        }
    }

    #pragma unroll
    for (int c = 0; c < 2; c++) {
        int col = (wv * 2 + c) * 16 + arow;
        float bir = bi[col],       bhr = bh[col];
        float biz = bi[128 + col], bhz = bh[128 + col];
        float bin_ = bi[256 + col], bhn_ = bh[256 + col];
        #pragma unroll
        for (int rt = 0; rt < 2; rt++)
            #pragma unroll
            for (int rg = 0; rg < 4; rg++) {
                int row = rt * 16 + kg * 4 + rg;
                int rr = r0 + row;
                if (rr < cnt) {
                    float r_ = 1.f / (1.f + expf(-(aR[c][rt][rg] + bir + bhr)));
                    float zg = 1.f / (1.f + expf(-(aZ[c][rt][rg] + biz + bhz)));
                    float ng = tanhf(aNi[c][rt][rg] + bin_ + r_ * (aNh[c][rt][rg] + bhn_));
                    float om = memory[(size_t)sn[row] * 128 + col];
                    new_mem[(size_t)rr * 128 + col] = (1.f - zg) * ng + zg * om;
                }
            }
    }
}

// Stage 2: unchanged from R1 (8 queries/block, folded Wk/Wv, online softmax).
__global__ void k_stage2(const int* __restrict__ src_nodes, const int* __restrict__ dst_nodes,
                         const int* __restrict__ neg_nodes, const int* __restrict__ edge_times,
                         const int* __restrict__ neighbors, const int* __restrict__ nb_eidx,
                         const int* __restrict__ nb_et,
                         const int* __restrict__ inv, const float* __restrict__ new_mem,
                         const float* __restrict__ memory, const float* __restrict__ node_feats,
                         const float* __restrict__ edge_feats,
                         const float* __restrict__ time_w, const float* __restrict__ time_b,
                         const float* __restrict__ Wq, const float* __restrict__ bq,
                         const float* __restrict__ Wk, const float* __restrict__ bk,
                         const float* __restrict__ Wv, const float* __restrict__ bv,
                         const float* __restrict__ Wo, const float* __restrict__ bo,
                         const float* __restrict__ mW1, const float* __restrict__ mb1,
                         const float* __restrict__ mW2, const float* __restrict__ mb2,
                         float* __restrict__ out)
{
    __shared__ float sfeat[8][128];
    __shared__ float buf256[8][256];
    __shared__ float buf256b[8][256];
    __shared__ float qk[8][768];
    __shared__ float kin[8][384];
    __shared__ float tss[8];
    __shared__ int nodeid[8];
    __shared__ int allm[8];

    int tid = threadIdx.x;
    int q0 = blockIdx.x * 8;

    if (tid < 8) {
        int q = q0 + tid;
        int node = (q < BB) ? src_nodes[q] : (q < 2 * BB) ? dst_nodes[q - BB] : neg_nodes[q - 2 * BB];
        nodeid[tid] = node;
        tss[tid] = (float)edge_times[q & (BB - 1)];
        int am = 1;
        for (int j = 0; j < KK; j++) if (neighbors[(size_t)q * KK + j] != 0) am = 0;
        allm[tid] = am;
    }
    __syncthreads();

    for (int x = tid; x < 8 * 128; x += 256) {
        int b = x >> 7, c = x & 127;
        int n = nodeid[b];
        int iv = inv[n];
        float mv = (iv >= 0) ? new_mem[(size_t)iv * 128 + c] : memory[(size_t)n * 128 + c];
        float sf = mv + node_feats[(size_t)n * 128 + c];
        sfeat[b][c] = sf;
        buf256[b][c] = sf;
        buf256[b][128 + c] = cosf(time_b[c]);
    }
    __syncthreads();

    {
        int c = tid;
        float acc[8];
        float bb = bq[c];
        #pragma unroll
        for (int b = 0; b < 8; b++) acc[b] = bb;
        const float4* w = (const float4*)(Wq + (size_t)c * 256);
        for (int k4 = 0; k4 < 64; k4++) {
            float4 wv = w[k4];
            #pragma unroll
            for (int b = 0; b < 8; b++) {
                float4 av = *((const float4*)&buf256[b][k4 * 4]);
                acc[b] += dot4(av, wv);
            }
        }
        #pragma unroll
        for (int b = 0; b < 8; b++) buf256b[b][c] = acc[b];
    }
    __syncthreads();

    int lane = tid & 15;
    int gb = tid >> 5;
    int gh = (tid >> 4) & 1;
    float cb = 0.f;
    #pragma unroll
    for (int i = 0; i < 8; i++) {
        int e = lane + 16 * i;
        cb += buf256b[gb][gh * 128 + e] * bk[gh * 128 + e];
    }
    cb += __shfl_xor(cb, 1, 16);
    cb += __shfl_xor(cb, 2, 16);
    cb += __shfl_xor(cb, 4, 16);
    cb += __shfl_xor(cb, 8, 16);

    {
        float qa[3][8];
        #pragma unroll
        for (int s = 0; s < 3; s++)
            #pragma unroll
            for (int b = 0; b < 8; b++) qa[s][b] = 0.f;
        #pragma unroll
        for (int s = 0; s < 3; s++) {
            int hj = tid + s * 256;
            int h = hj / 384, j = hj % 384;
            const float* wcol = Wk + (size_t)h * 128 * 384 + j;
            for (int c4 = 0; c4 < 32; c4++) {
                float w0 = wcol[(size_t)(c4 * 4 + 0) * 384];
                float w1 = wcol[(size_t)(c4 * 4 + 1) * 384];
                float w2 = wcol[(size_t)(c4 * 4 + 2) * 384];
                float w3 = wcol[(size_t)(c4 * 4 + 3) * 384];
                #pragma unroll
                for (int b = 0; b < 8; b++) {
                    float4 qv = *((const float4*)&buf256b[b][h * 128 + c4 * 4]);
                    qa[s][b] += qv.x * w0 + qv.y * w1 + qv.z * w2 + qv.w * w3;
                }
            }
        }
        #pragma unroll
        for (int s = 0; s < 3; s++) {
            int hj = tid + s * 256;
            #pragma unroll
            for (int b = 0; b < 8; b++) qk[b][hj] = qa[s][b];
        }
    }
    __syncthreads();

    float m_run = -3.0e38f, l_run = 0.f;
    float wacc[24];
    #pragma unroll
    for (int i = 0; i < 24; i++) wacc[i] = 0.f;
    int b2 = tid >> 5, l32 = tid & 31;
    const float inv_sqrt = 0.08838834764831845f;

    for (int j = 0; j < KK; j++) {
        {
            int row = q0 + b2;
            int nb = neighbors[(size_t)row * KK + j];
            int eidx = nb_eidx[(size_t)row * KK + j];
            float dtf = tss[b2] - (float)nb_et[(size_t)row * KK + j];
            int iv = inv[nb];
            #pragma unroll
            for (int i = 0; i < 4; i++) {
                int c = l32 + 32 * i;
                float mv = (iv >= 0) ? new_mem[(size_t)iv * 128 + c] : memory[(size_t)nb * 128 + c];
                kin[b2][c] = mv + node_feats[(size_t)nb * 128 + c];
            }
            #pragma unroll
            for (int i = 0; i < 4; i++) {
                int c = l32 + 32 * i;
                kin[b2][128 + c] = tenc(dtf, time_w[c], time_b[c]);
            }
            #pragma unroll
            for (int i = 0; i < 4; i++) {
                int c = l32 + 32 * i;
                kin[b2][256 + c] = edge_feats[(size_t)eidx * 128 + c];
            }
        }
        __syncthreads();

        float part = 0.f;
        #pragma unroll
        for (int i = 0; i < 24; i++) {
            int e = lane + 16 * i;
            part += qk[gb][gh * 384 + e] * kin[gb][e];
        }
        part += __shfl_xor(part, 1, 16);
        part += __shfl_xor(part, 2, 16);
        part += __shfl_xor(part, 4, 16);
        part += __shfl_xor(part, 8, 16);
        float s = (part + cb) * inv_sqrt;
        int nbq = neighbors[(size_t)(q0 + gb) * KK + j];
        if (nbq == 0) s = -1e9f;
        float m_new = fmaxf(m_run, s);
        float scale = expf(m_run - m_new);
        float p = expf(s - m_new);
        l_run = l_run * scale + p;
        #pragma unroll
        for (int i = 0; i < 24; i++) {
            wacc[i] = wacc[i] * scale + p * kin[gb][lane + 16 * i];
        }
        m_run = m_new;
        __syncthreads();
    }
    {
        float linv = 1.f / l_run;
        #pragma unroll
        for (int i = 0; i < 24; i++) qk[gb][gh * 384 + lane + 16 * i] = wacc[i] * linv;
    }
    __syncthreads();

    {
        int h = tid >> 7;
        float acc[8];
        float bb = bv[tid];
        #pragma unroll
        for (int b = 0; b < 8; b++) acc[b] = bb;
        const float4* w = (const float4*)(Wv + (size_t)tid * 384);
        for (int k4 = 0; k4 < 96; k4++) {
            float4 wv = w[k4];
            #pragma unroll
            for (int b = 0; b < 8; b++) {
                float4 av = *((const float4*)&qk[b][h * 384 + k4 * 4]);
                acc[b] += dot4(av, wv);
            }
        }
        #pragma unroll
        for (int b = 0; b < 8; b++) buf256[b][tid] = acc[b];
    }
    __syncthreads();

    {
        int c = tid;
        float acc[8];
        float bb = bo[c];
        #pragma unroll
        for (int b = 0; b < 8; b++) acc[b] = bb;
        const float4* w = (const float4*)(Wo + (size_t)c * 256);
        for (int k4 = 0; k4 < 64; k4++) {
            float4 wv = w[k4];
            #pragma unroll
            for (int b = 0; b < 8; b++) {
                float4 av = *((const float4*)&buf256[b][k4 * 4]);
                acc[b] += dot4(av, wv);
            }
        }
        #pragma unroll
        for (int b = 0; b < 8; b++) buf256b[b][c] = allm[b] ? 0.f : acc[b];
    }
    __syncthreads();

    float* hm = &kin[0][0];
    {
        int half = tid >> 7, c = tid & 127;
        float acc[4];
        float bb = mb1[c];
        #pragma unroll
        for (int r = 0; r < 4; r++) acc[r] = bb;
        const float4* w = (const float4*)(mW1 + (size_t)c * 384);
        for (int k4 = 0; k4 < 64; k4++) {
            float4 wv = w[k4];
            #pragma unroll
            for (int r = 0; r < 4; r++) {
                float4 av = *((const float4*)&buf256b[half * 4 + r][k4 * 4]);
                acc[r] += dot4(av, wv);
            }
        }
        for (int k4 = 64; k4 < 96; k4++) {
            float4 wv = w[k4];
            #pragma unroll
            for (int r = 0; r < 4; r++) {
                float4 av = *((const float4*)&sfeat[half * 4 + r][(k4 - 64) * 4]);
                acc[r] += dot4(av, wv);
            }
        }
        #pragma unroll
        for (int r = 0; r < 4; r++) hm[(half * 4 + r) * 128 + c] = fmaxf(acc[r], 0.f);
    }
    __syncthreads();

    {
        int half = tid >> 7, c = tid & 127;
        float acc[4];
        float bb = mb2[c];
        #pragma unroll
        for (int r = 0; r < 4; r++) acc[r] = bb;
        const float4* w = (const float4*)(mW2 + (size_t)c * 128);
        for (int k4 = 0; k4 < 32; k4++) {
            float4 wv = w[k4];
            #pragma unroll
            for (int r = 0; r < 4; r++) {
                float4 av = *((const float4*)&hm[(half * 4 + r) * 128 + k4 * 4]);
                acc[r] += dot4(av, wv);
            }
        }
        #pragma unroll
        for (int r = 0; r < 4; r++)
            out[(size_t)(q0 + half * 4 + r) * 128 + c] = acc[r];
    }
}

extern "C" void kernel_launch(void* const* d_in, const int* in_sizes, int n_in,
                              void* d_out, int out_size, void* d_ws, size_t ws_size,
                              hipStream_t stream) {
    (void)in_sizes; (void)n_in; (void)out_size; (void)ws_size;
    const int* src_nodes  = (const int*)d_in[0];
    const int* dst_nodes  = (const int*)d_in[1];
    const int* neg_nodes  = (const int*)d_in[2];
    const int* edge_times = (const int*)d_in[3];
    const int* neighbors  = (const int*)d_in[4];
    const int* nb_eidx    = (const int*)d_in[5];
    const int* nb_et      = (const int*)d_in[6];
    const int* msg_src    = (const int*)d_in[7];
    const int* msg_dst    = (const int*)d_in[8];
    const int* msg_eidx   = (const int*)d_in[9];
    const int* msg_t      = (const int*)d_in[10];
    const int* last_update= (const int*)d_in[11];
    const float* node_feats = (const float*)d_in[12];
    const float* edge_feats = (const float*)d_in[13];
    const float* memory     = (const float*)d_in[14];
    const float* time_w = (const float*)d_in[15];
    const float* time_b = (const float*)d_in[16];
    const float* W1 = (const float*)d_in[17];
    const float* b1 = (const float*)d_in[18];
    const float* W2 = (const float*)d_in[19];
    const float* b2 = (const float*)d_in[20];
    const float* gWi = (const float*)d_in[21];
    const float* gWh = (const float*)d_in[22];
    const float* gbi = (const float*)d_in[23];
    const float* gbh = (const float*)d_in[24];
    const float* Wq = (const float*)d_in[25];
    const float* bq = (const float*)d_in[26];
    const float* Wk = (const float*)d_in[27];
    const float* bk = (const float*)d_in[28];
    const float* Wv = (const float*)d_in[29];
    const float* bv = (const float*)d_in[30];
    const float* Wo = (const float*)d_in[31];
    const float* bo = (const float*)d_in[32];
    const float* mW1 = (const float*)d_in[33];
    const float* mb1 = (const float*)d_in[34];
    const float* mW2 = (const float*)d_in[35];
    const float* mb2 = (const float*)d_in[36];
    float* out = (float*)d_out;

    char* w = (char*)d_ws;
    int* lastpos = (int*)w;
    int* inv  = lastpos + NN;
    int* comp = inv + NN;
    int* count = comp + NN;
    size_t off = ((size_t)(3 * NN + 1) * 4 + 255) & ~(size_t)255;
    float* new_mem = (float*)(w + off);               // MM*128 f32 (51.2 MB)
    size_t woff = off + (size_t)MM * 128 * 4;
    _Float16* W1h = (_Float16*)(w + woff);            // 256KB
    _Float16* W2h = W1h + 131072;                     // 64KB
    _Float16* Wih = W2h + 32768;                      // 96KB
    _Float16* Whh = Wih + 49152;                      // 96KB

    k_init<<<dim3((NN + 255) / 256), dim3(256), 0, stream>>>(lastpos, inv, count);
    k_scatter<<<dim3((MM + 255) / 256), dim3(256), 0, stream>>>(msg_src, lastpos);
    k_compact<<<dim3((NN + 255) / 256), dim3(256), 0, stream>>>(lastpos, inv, comp, count);
    k_cvtw<<<dim3(256), dim3(256), 0, stream>>>(W1, W2, gWi, gWh, W1h, W2h, Wih, Whh);
    k_stage1<<<dim3((MM + 31) / 32), dim3(256), 0, stream>>>(
        comp, count, lastpos, msg_dst, msg_eidx, msg_t, last_update,
        memory, edge_feats, time_w, time_b,
        W1h, b1, W2h, b2, Wih, Whh, gbi, gbh, new_mem);
    k_stage2<<<dim3(Q3 / 8), dim3(256), 0, stream>>>(
        src_nodes, dst_nodes, neg_nodes, edge_times, neighbors, nb_eidx, nb_et,
        inv, new_mem, memory, node_feats, edge_feats, time_w, time_b,
        Wq, bq, Wk, bk, Wv, bv, Wo, bo, mW1, mb1, mW2, mb2, out);
}

// Round 3
// 600.601 us; speedup vs baseline: 3.8756x; 1.4262x over previous
//
#include <hip/hip_runtime.h>
#include <math.h>

#define NN 200000
#define EEDGE 500000
#define BB 4096
#define KK 20
#define MM 100000
#define Q3 (3*BB)

typedef _Float16 __attribute__((ext_vector_type(8))) f16x8;
typedef _Float16 __attribute__((ext_vector_type(4))) f16x4;
typedef float __attribute__((ext_vector_type(4))) f32x4;

#define MFMA16(a,b,c) __builtin_amdgcn_mfma_f32_16x16x32_f16(a,b,c,0,0,0)

// time encoding matching numpy rounding — NO fma contraction (args ~5e6).
__device__ __forceinline__ float tenc(float dt, float w, float b) {
    float p = __fmul_rn(dt, w);
    float a = __fadd_rn(p, b);
    return cosf(a);
}

__device__ __forceinline__ f32x4 z4() {
    f32x4 v; v[0] = 0.f; v[1] = 0.f; v[2] = 0.f; v[3] = 0.f; return v;
}

__global__ void k_init(int* lastpos, int* inv, int* count) {
    int i = blockIdx.x * 256 + threadIdx.x;
    if (i < NN) { lastpos[i] = -1; inv[i] = -1; }
    if (i == 0) *count = 0;
}

__global__ void k_scatter(const int* __restrict__ msg_src, int* __restrict__ lastpos) {
    int i = blockIdx.x * 256 + threadIdx.x;
    if (i < MM) atomicMax(&lastpos[msg_src[i]], i);
}

__global__ void k_compact(const int* __restrict__ lastpos, int* __restrict__ inv,
                          int* __restrict__ comp, int* __restrict__ count) {
    int n = blockIdx.x * 256 + threadIdx.x;
    if (n < NN && lastpos[n] >= 0) {
        int j = atomicAdd(count, 1);
        comp[j] = n;
        inv[n] = j;
    }
}

// convert all weights f32 -> f16 (Wk additionally transposed) into one f16 pool
__global__ void k_cvtw(const float* __restrict__ W1, const float* __restrict__ W2,
                       const float* __restrict__ Wi, const float* __restrict__ Wh,
                       const float* __restrict__ Wq, const float* __restrict__ Wv,
                       const float* __restrict__ Wo, const float* __restrict__ mW1,
                       const float* __restrict__ mW2, const float* __restrict__ Wk,
                       _Float16* __restrict__ dst) {
    int base = (blockIdx.x * 256 + threadIdx.x) * 4;
    #pragma unroll
    for (int u = 0; u < 4; u++) {
        int e = base + u;
        float v;
        if (e < 131072)      v = W1[e];
        else if (e < 163840) v = W2[e - 131072];
        else if (e < 212992) v = Wi[e - 163840];
        else if (e < 262144) v = Wh[e - 212992];
        else if (e < 327680) v = Wq[e - 262144];
        else if (e < 425984) v = Wv[e - 327680];
        else if (e < 491520) v = Wo[e - 425984];
        else if (e < 540672) v = mW1[e - 491520];
        else if (e < 557056) v = mW2[e - 540672];
        else {                               // Wkt[h][c][j] = Wk[h*128+j][c]
            int le = e - 557056;
            int h = le / 49152, rem = le % 49152;
            int c = rem / 128, j = rem % 128;
            v = Wk[(size_t)(h * 128 + j) * 384 + c];
        }
        dst[e] = (_Float16)v;
    }
}

// ---------------- Stage 1 (unchanged from R2) ----------------
__device__ __forceinline__ int SWA(int r, int byteofs) {
    return r * 1024 + (byteofs ^ ((r & 7) << 4));
}

__global__ __launch_bounds__(256, 3)
void k_stage1(const int* __restrict__ comp, const int* __restrict__ count,
              const int* __restrict__ lastpos,
              const int* __restrict__ msg_dst, const int* __restrict__ msg_eidx,
              const int* __restrict__ msg_t, const int* __restrict__ last_update,
              const float* __restrict__ memory, const float* __restrict__ edge_feats,
              const float* __restrict__ time_w, const float* __restrict__ time_b,
              const _Float16* __restrict__ W1h, const float* __restrict__ b1,
              const _Float16* __restrict__ W2h, const float* __restrict__ b2,
              const _Float16* __restrict__ Wih, const _Float16* __restrict__ Whh,
              const float* __restrict__ bi, const float* __restrict__ bh,
              float* __restrict__ new_mem)
{
    __shared__ char rawb[32 * 1024];
    __shared__ int sn[32], sd[32], se[32];
    __shared__ float sdt[32];

    int cnt = *count;
    int r0 = blockIdx.x * 32;
    if (r0 >= cnt) return;
    int tid = threadIdx.x;

    if (tid < 32) {
        int rr = r0 + tid;
        int j = (rr < cnt) ? rr : r0;
        int n = comp[j];
        int idx = lastpos[n];
        sn[tid] = n;
        sd[tid] = msg_dst[idx];
        se[tid] = msg_eidx[idx];
        sdt[tid] = (float)(msg_t[idx] - last_update[n]);
    }
    __syncthreads();

    #pragma unroll
    for (int t = 0; t < 8; t++) {
        int gi = tid + t * 256;
        int r = gi >> 6, g = gi & 63;
        char* dst = rawb + SWA(r, g * 16);
        f16x8 h;
        if (g < 48) {
            const float* src;
            if (g < 16)      src = memory + (size_t)sn[r] * 128 + g * 8;
            else if (g < 32) src = memory + (size_t)sd[r] * 128 + (g - 16) * 8;
            else             src = edge_feats + (size_t)se[r] * 128 + (g - 32) * 8;
            float4 a = *(const float4*)src;
            float4 b = *(const float4*)(src + 4);
            h[0] = (_Float16)a.x; h[1] = (_Float16)a.y; h[2] = (_Float16)a.z; h[3] = (_Float16)a.w;
            h[4] = (_Float16)b.x; h[5] = (_Float16)b.y; h[6] = (_Float16)b.z; h[7] = (_Float16)b.w;
        } else {
            int c = (g - 48) * 8;
            float4 w0 = *(const float4*)(time_w + c);
            float4 w1 = *(const float4*)(time_w + c + 4);
            float4 t0 = *(const float4*)(time_b + c);
            float4 t1 = *(const float4*)(time_b + c + 4);
            float dt = sdt[r];
            h[0] = (_Float16)tenc(dt, w0.x, t0.x); h[1] = (_Float16)tenc(dt, w0.y, t0.y);
            h[2] = (_Float16)tenc(dt, w0.z, t0.z); h[3] = (_Float16)tenc(dt, w0.w, t0.w);
            h[4] = (_Float16)tenc(dt, w1.x, t1.x); h[5] = (_Float16)tenc(dt, w1.y, t1.y);
            h[6] = (_Float16)tenc(dt, w1.z, t1.z); h[7] = (_Float16)tenc(dt, w1.w, t1.w);
        }
        *(f16x8*)dst = h;
    }
    __syncthreads();

    int wv = tid >> 6, lane = tid & 63;
    int arow = lane & 15, kg = lane >> 4;

    f32x4 acc1[4][2];
    #pragma unroll
    for (int c = 0; c < 4; c++) { acc1[c][0] = z4(); acc1[c][1] = z4(); }
    for (int ks = 0; ks < 16; ks++) {
        f16x8 a0 = *(const f16x8*)(rawb + SWA(arow,      ks * 64 + kg * 16));
        f16x8 a1 = *(const f16x8*)(rawb + SWA(16 + arow, ks * 64 + kg * 16));
        #pragma unroll
        for (int c = 0; c < 4; c++) {
            int col = (wv * 4 + c) * 16 + arow;
            f16x8 b = *(const f16x8*)(W1h + (size_t)col * 512 + ks * 32 + kg * 8);
            acc1[c][0] = MFMA16(a0, b, acc1[c][0]);
            acc1[c][1] = MFMA16(a1, b, acc1[c][1]);
        }
    }
    __syncthreads();

    #pragma unroll
    for (int c = 0; c < 4; c++) {
        int col = (wv * 4 + c) * 16 + arow;
        float bb = b1[col];
        #pragma unroll
        for (int rt = 0; rt < 2; rt++)
            #pragma unroll
            for (int rg = 0; rg < 4; rg++) {
                int row = rt * 16 + kg * 4 + rg;
                float v = acc1[c][rt][rg] + bb;
                v = fmaxf(v, 0.f);
                *(_Float16*)(rawb + SWA(row, 384 + col * 2)) = (_Float16)v;
            }
    }
    __syncthreads();

    f32x4 acc2[2][2];
    #pragma unroll
    for (int c = 0; c < 2; c++) { acc2[c][0] = z4(); acc2[c][1] = z4(); }
    for (int ks = 0; ks < 8; ks++) {
        f16x8 a0 = *(const f16x8*)(rawb + SWA(arow,      384 + ks * 64 + kg * 16));
        f16x8 a1 = *(const f16x8*)(rawb + SWA(16 + arow, 384 + ks * 64 + kg * 16));
        #pragma unroll
        for (int c = 0; c < 2; c++) {
            int col = (wv * 2 + c) * 16 + arow;
            f16x8 b = *(const f16x8*)(W2h + (size_t)col * 256 + ks * 32 + kg * 8);
            acc2[c][0] = MFMA16(a0, b, acc2[c][0]);
            acc2[c][1] = MFMA16(a1, b, acc2[c][1]);
        }
    }
    __syncthreads();

    #pragma unroll
    for (int c = 0; c < 2; c++) {
        int col = (wv * 2 + c) * 16 + arow;
        float bb = b2[col];
        #pragma unroll
        for (int rt = 0; rt < 2; rt++)
            #pragma unroll
            for (int rg = 0; rg < 4; rg++) {
                int row = rt * 16 + kg * 4 + rg;
                *(_Float16*)(rawb + SWA(row, 384 + col * 2)) =
                    (_Float16)(acc2[c][rt][rg] + bb);
            }
    }
    __syncthreads();

    f32x4 aR[2][2], aZ[2][2], aNi[2][2], aNh[2][2];
    #pragma unroll
    for (int c = 0; c < 2; c++)
        #pragma unroll
        for (int rt = 0; rt < 2; rt++) {
            aR[c][rt] = z4(); aZ[c][rt] = z4(); aNi[c][rt] = z4(); aNh[c][rt] = z4();
        }
    for (int ks = 0; ks < 4; ks++) {
        f16x8 m0 = *(const f16x8*)(rawb + SWA(arow,      384 + ks * 64 + kg * 16));
        f16x8 m1 = *(const f16x8*)(rawb + SWA(16 + arow, 384 + ks * 64 + kg * 16));
        f16x8 h0 = *(const f16x8*)(rawb + SWA(arow,      ks * 64 + kg * 16));
        f16x8 h1v = *(const f16x8*)(rawb + SWA(16 + arow, ks * 64 + kg * 16));
        #pragma unroll
        for (int c = 0; c < 2; c++) {
            int col = (wv * 2 + c) * 16 + arow;
            const _Float16* pi = Wih + (size_t)col * 128 + ks * 32 + kg * 8;
            const _Float16* ph = Whh + (size_t)col * 128 + ks * 32 + kg * 8;
            f16x8 bri = *(const f16x8*)pi;
            f16x8 bzi = *(const f16x8*)(pi + 128 * 128);
            f16x8 bni = *(const f16x8*)(pi + 256 * 128);
            f16x8 brh = *(const f16x8*)ph;
            f16x8 bzh = *(const f16x8*)(ph + 128 * 128);
            f16x8 bnh = *(const f16x8*)(ph + 256 * 128);
            aR[c][0] = MFMA16(m0, bri, aR[c][0]);  aR[c][0] = MFMA16(h0, brh, aR[c][0]);
            aR[c][1] = MFMA16(m1, bri, aR[c][1]);  aR[c][1] = MFMA16(h1v, brh, aR[c][1]);
            aZ[c][0] = MFMA16(m0, bzi, aZ[c][0]);  aZ[c][0] = MFMA16(h0, bzh, aZ[c][0]);
            aZ[c][1] = MFMA16(m1, bzi, aZ[c][1]);  aZ[c][1] = MFMA16(h1v, bzh, aZ[c][1]);
            aNi[c][0] = MFMA16(m0, bni, aNi[c][0]);
            aNi[c][1] = MFMA16(m1, bni, aNi[c][1]);
            aNh[c][0] = MFMA16(h0, bnh, aNh[c][0]);
            aNh[c][1] = MFMA16(h1v, bnh, aNh[c][1]);
        }
    }

    #pragma unroll
    for (int c = 0; c < 2; c++) {
        int col = (wv * 2 + c) * 16 + arow;
        float bir = bi[col],       bhr = bh[col];
        float biz = bi[128 + col], bhz = bh[128 + col];
        float bin_ = bi[256 + col], bhn_ = bh[256 + col];
        #pragma unroll
        for (int rt = 0; rt < 2; rt++)
            #pragma unroll
            for (int rg = 0; rg < 4; rg++) {
                int row = rt * 16 + kg * 4 + rg;
                int rr = r0 + row;
                if (rr < cnt) {
                    float r_ = 1.f / (1.f + expf(-(aR[c][rt][rg] + bir + bhr)));
                    float zg = 1.f / (1.f + expf(-(aZ[c][rt][rg] + biz + bhz)));
                    float ng = tanhf(aNi[c][rt][rg] + bin_ + r_ * (aNh[c][rt][rg] + bhn_));
                    float om = memory[(size_t)sn[row] * 128 + col];
                    new_mem[(size_t)rr * 128 + col] = (1.f - zg) * ng + zg * om;
                }
            }
    }
}

// ---------------- Stage 2 ----------------
// k2a: build q_in[12288][256] f16 (sfeat | cos(time_b)) and acat cols 256-383 = sfeat
__global__ void k2a(const int* __restrict__ src_nodes, const int* __restrict__ dst_nodes,
                    const int* __restrict__ neg_nodes, const int* __restrict__ inv,
                    const float* __restrict__ new_mem, const float* __restrict__ memory,
                    const float* __restrict__ node_feats, const float* __restrict__ time_b,
                    _Float16* __restrict__ q_in, _Float16* __restrict__ acat)
{
    __shared__ int snode[32], siv[32];
    int tid = threadIdx.x;
    int r0 = blockIdx.x * 32;
    if (tid < 32) {
        int q = r0 + tid;
        int node = (q < BB) ? src_nodes[q] : (q < 2 * BB) ? dst_nodes[q - BB] : neg_nodes[q - 2 * BB];
        snode[tid] = node;
        siv[tid] = inv[node];
    }
    __syncthreads();
    #pragma unroll
    for (int it = 0; it < 4; it++) {
        int gi = tid + it * 256;
        int r = gi >> 5, ch = gi & 31;
        int c = ch * 4;
        int node = snode[r], iv = siv[r];
        const float* mp = (iv >= 0) ? (new_mem + (size_t)iv * 128) : (memory + (size_t)node * 128);
        float4 mv = *(const float4*)(mp + c);
        float4 nf = *(const float4*)(node_feats + (size_t)node * 128 + c);
        f16x4 sf;
        sf[0] = (_Float16)(mv.x + nf.x); sf[1] = (_Float16)(mv.y + nf.y);
        sf[2] = (_Float16)(mv.z + nf.z); sf[3] = (_Float16)(mv.w + nf.w);
        size_t q = (size_t)(r0 + r);
        *(f16x4*)(q_in + q * 256 + c) = sf;
        *(f16x4*)(acat + q * 384 + 256 + c) = sf;
        float4 tb = *(const float4*)(time_b + c);
        f16x4 te;
        te[0] = (_Float16)cosf(tb.x); te[1] = (_Float16)cosf(tb.y);
        te[2] = (_Float16)cosf(tb.z); te[3] = (_Float16)cosf(tb.w);
        *(f16x4*)(q_in + q * 256 + 128 + c) = te;
    }
}

// generic 32-row-tile MFMA GEMM: C[row][coff+cg] = A[row][aoff..aoff+KD) . B[cg][0..KD) + bias
template<int KD, int NFRAG, bool RELU>
__global__ __launch_bounds__(256, 2)
void k_gemm(const _Float16* __restrict__ A, int lda, int a_ys,
            const _Float16* __restrict__ B, int b_ys,
            const float* __restrict__ bias, int bias_ys,
            _Float16* __restrict__ C, int ldc, int c_ys,
            float* __restrict__ C32,
            const int* __restrict__ rowmask)
{
    constexpr int ROWB = KD * 2;
    __shared__ char As[32 * ROWB];
    int tid = threadIdx.x;
    int r0 = blockIdx.x * 32;
    int aoff = blockIdx.y * a_ys;
    const _Float16* Bp = B + (size_t)blockIdx.y * b_ys;
    int coff = blockIdx.y * c_ys;

    #pragma unroll
    for (int t = 0; t < (32 * KD / 8) / 256; t++) {
        int gi = tid + t * 256;
        int r = gi / (KD / 8), g = gi % (KD / 8);
        f16x8 v = *(const f16x8*)(A + (size_t)(r0 + r) * lda + aoff + g * 8);
        *(f16x8*)(&As[r * ROWB + ((g * 16) ^ ((r & 7) << 4))]) = v;
    }
    __syncthreads();

    int wv = tid >> 6, lane = tid & 63;
    int arow = lane & 15, kg = lane >> 4;
    f32x4 acc[NFRAG][2];
    #pragma unroll
    for (int c = 0; c < NFRAG; c++) { acc[c][0] = z4(); acc[c][1] = z4(); }

    #pragma unroll
    for (int ks = 0; ks < KD / 32; ks++) {
        f16x8 a0 = *(const f16x8*)(&As[arow * ROWB + ((ks * 64 + kg * 16) ^ ((arow & 7) << 4))]);
        f16x8 a1 = *(const f16x8*)(&As[(16 + arow) * ROWB + ((ks * 64 + kg * 16) ^ ((arow & 7) << 4))]);
        #pragma unroll
        for (int c = 0; c < NFRAG; c++) {
            int cg = (wv * NFRAG + c) * 16 + arow;
            f16x8 b = *(const f16x8*)(Bp + (size_t)cg * KD + ks * 32 + kg * 8);
            acc[c][0] = MFMA16(a0, b, acc[c][0]);
            acc[c][1] = MFMA16(a1, b, acc[c][1]);
        }
    }

    #pragma unroll
    for (int c = 0; c < NFRAG; c++) {
        int cg = (wv * NFRAG + c) * 16 + arow;
        float bb = bias ? bias[blockIdx.y * bias_ys + cg] : 0.f;
        #pragma unroll
        for (int rt = 0; rt < 2; rt++)
            #pragma unroll
            for (int rg = 0; rg < 4; rg++) {
                int grow = r0 + rt * 16 + kg * 4 + rg;
                float v = acc[c][rt][rg] + bb;
                if (RELU) v = fmaxf(v, 0.f);
                if (rowmask && rowmask[grow]) v = 0.f;
                if (C)   C[(size_t)grow * ldc + coff + cg] = (_Float16)v;
                if (C32) C32[(size_t)grow * ldc + coff + cg] = v;
            }
    }
}

// k2d: attention core. 1 query per wave, head per half-wave, no LDS, no barriers.
// Reads qk[12288][768] f16, overwrites it with normalized wsum f16. Writes allm.
__global__ __launch_bounds__(256)
void k2d(const int* __restrict__ neighbors, const int* __restrict__ nb_eidx,
         const int* __restrict__ nb_et, const int* __restrict__ edge_times,
         const int* __restrict__ inv, const float* __restrict__ new_mem,
         const float* __restrict__ memory, const float* __restrict__ node_feats,
         const float* __restrict__ edge_feats, const float* __restrict__ time_w,
         const float* __restrict__ time_b, const float* __restrict__ bk,
         const _Float16* __restrict__ qbuf, _Float16* __restrict__ qk_wsum,
         int* __restrict__ allm)
{
    int tid = threadIdx.x;
    int qi = blockIdx.x * 4 + (tid >> 6);
    int lane = tid & 63;
    int h = lane >> 5, l32 = lane & 31;
    int c0 = l32 * 4;

    float4 tw = *(const float4*)(time_w + c0);
    float4 tb = *(const float4*)(time_b + c0);

    const _Float16* qkp = qk_wsum + (size_t)qi * 768 + h * 384;
    f16x4 t0 = *(const f16x4*)(qkp + c0);
    f16x4 t1 = *(const f16x4*)(qkp + 128 + c0);
    f16x4 t2 = *(const f16x4*)(qkp + 256 + c0);
    float qk0[4], qk1[4], qk2[4];
    #pragma unroll
    for (int t = 0; t < 4; t++) { qk0[t] = (float)t0[t]; qk1[t] = (float)t1[t]; qk2[t] = (float)t2[t]; }

    // cb = q_h . bk_h
    f16x4 qv = *(const f16x4*)(qbuf + (size_t)qi * 256 + h * 128 + c0);
    float4 bkv = *(const float4*)(bk + h * 128 + c0);
    float cb = (float)qv[0] * bkv.x + (float)qv[1] * bkv.y +
               (float)qv[2] * bkv.z + (float)qv[3] * bkv.w;
    cb += __shfl_xor(cb, 1, 32);
    cb += __shfl_xor(cb, 2, 32);
    cb += __shfl_xor(cb, 4, 32);
    cb += __shfl_xor(cb, 8, 32);
    cb += __shfl_xor(cb, 16, 32);

    float ts = (float)edge_times[qi & (BB - 1)];
    float m_run = -3.0e38f, l_run = 0.f;
    float w0[4] = {0,0,0,0}, w1[4] = {0,0,0,0}, w2[4] = {0,0,0,0};
    int anyv = 0;
    const float inv_sqrt = 0.08838834764831845f;

    for (int j = 0; j < KK; j++) {
        int nb = neighbors[qi * KK + j];          // wave-uniform -> scalar loads
        int eidx = nb_eidx[qi * KK + j];
        float dtf = ts - (float)nb_et[qi * KK + j];
        int iv = inv[nb];
        anyv |= (nb != 0);

        const float* mp = (iv >= 0) ? (new_mem + (size_t)iv * 128) : (memory + (size_t)nb * 128);
        float4 mv = *(const float4*)(mp + c0);
        float4 nf = *(const float4*)(node_feats + (size_t)nb * 128 + c0);
        float4 ef = *(const float4*)(edge_feats + (size_t)eidx * 128 + c0);
        float k0[4] = { mv.x + nf.x, mv.y + nf.y, mv.z + nf.z, mv.w + nf.w };
        float k1[4] = { tenc(dtf, tw.x, tb.x), tenc(dtf, tw.y, tb.y),
                        tenc(dtf, tw.z, tb.z), tenc(dtf, tw.w, tb.w) };
        float k2[4] = { ef.x, ef.y, ef.z, ef.w };

        float sp = 0.f;
        #pragma unroll
        for (int t = 0; t < 4; t++)
            sp += qk0[t] * k0[t] + qk1[t] * k1[t] + qk2[t] * k2[t];
        sp += __shfl_xor(sp, 1, 32);
        sp += __shfl_xor(sp, 2, 32);
        sp += __shfl_xor(sp, 4, 32);
        sp += __shfl_xor(sp, 8, 32);
        sp += __shfl_xor(sp, 16, 32);

        float s = (sp + cb) * inv_sqrt;
        if (nb == 0) s = -1e9f;
        float m_new = fmaxf(m_run, s);
        float sc = expf(m_run - m_new);
        float p = expf(s - m_new);
        l_run = l_run * sc + p;
        #pragma unroll
        for (int t = 0; t < 4; t++) {
            w0[t] = w0[t] * sc + p * k0[t];
            w1[t] = w1[t] * sc + p * k1[t];
            w2[t] = w2[t] * sc + p * k2[t];
        }
        m_run = m_new;
    }

    float linv = 1.f / l_run;
    _Float16* wp = qk_wsum + (size_t)qi * 768 + h * 384;   // overwrite qk (fully consumed)
    f16x4 o0, o1, o2;
    #pragma unroll
    for (int t = 0; t < 4; t++) {
        o0[t] = (_Float16)(w0[t] * linv);
        o1[t] = (_Float16)(w1[t] * linv);
        o2[t] = (_Float16)(w2[t] * linv);
    }
    *(f16x4*)(wp + c0) = o0;
    *(f16x4*)(wp + 128 + c0) = o1;
    *(f16x4*)(wp + 256 + c0) = o2;
    if (lane == 0) allm[qi] = anyv ? 0 : 1;
}

extern "C" void kernel_launch(void* const* d_in, const int* in_sizes, int n_in,
                              void* d_out, int out_size, void* d_ws, size_t ws_size,
                              hipStream_t stream) {
    (void)in_sizes; (void)n_in; (void)out_size; (void)ws_size;
    const int* src_nodes  = (const int*)d_in[0];
    const int* dst_nodes  = (const int*)d_in[1];
    const int* neg_nodes  = (const int*)d_in[2];
    const int* edge_times = (const int*)d_in[3];
    const int* neighbors  = (const int*)d_in[4];
    const int* nb_eidx    = (const int*)d_in[5];
    const int* nb_et      = (const int*)d_in[6];
    const int* msg_src    = (const int*)d_in[7];
    const int* msg_dst    = (const int*)d_in[8];
    const int* msg_eidx   = (const int*)d_in[9];
    const int* msg_t      = (const int*)d_in[10];
    const int* last_update= (const int*)d_in[11];
    const float* node_feats = (const float*)d_in[12];
    const float* edge_feats = (const float*)d_in[13];
    const float* memory     = (const float*)d_in[14];
    const float* time_w = (const float*)d_in[15];
    const float* time_b = (const float*)d_in[16];
    const float* W1 = (const float*)d_in[17];
    const float* b1 = (const float*)d_in[18];
    const float* W2 = (const float*)d_in[19];
    const float* b2 = (const float*)d_in[20];
    const float* gWi = (const float*)d_in[21];
    const float* gWh = (const float*)d_in[22];
    const float* gbi = (const float*)d_in[23];
    const float* gbh = (const float*)d_in[24];
    const float* Wq = (const float*)d_in[25];
    const float* bq = (const float*)d_in[26];
    const float* Wk = (const float*)d_in[27];
    const float* bk = (const float*)d_in[28];
    const float* Wv = (const float*)d_in[29];
    const float* bv = (const float*)d_in[30];
    const float* Wo = (const float*)d_in[31];
    const float* bo = (const float*)d_in[32];
    const float* mW1 = (const float*)d_in[33];
    const float* mb1 = (const float*)d_in[34];
    const float* mW2 = (const float*)d_in[35];
    const float* mb2 = (const float*)d_in[36];
    float* out = (float*)d_out;

    char* w = (char*)d_ws;
    int* lastpos = (int*)w;
    int* inv  = lastpos + NN;
    int* comp = inv + NN;
    int* count = comp + NN;
    size_t off = ((size_t)(3 * NN + 1) * 4 + 255) & ~(size_t)255;
    float* new_mem = (float*)(w + off);               // MM*128 f32 (51.2 MB)
    size_t woff = off + (size_t)MM * 128 * 4;

    _Float16* Hpool = (_Float16*)(w + woff);          // 655360 f16 weights
    _Float16* W1h  = Hpool;
    _Float16* W2h  = Hpool + 131072;
    _Float16* Wih  = Hpool + 163840;
    _Float16* Whh  = Hpool + 212992;
    _Float16* Wqh  = Hpool + 262144;
    _Float16* Wvh  = Hpool + 327680;
    _Float16* Woh  = Hpool + 425984;
    _Float16* mW1h = Hpool + 491520;
    _Float16* mW2h = Hpool + 540672;
    _Float16* Wkth = Hpool + 557056;
    size_t boff = woff + (size_t)655360 * 2;

    _Float16* qin_ctx = (_Float16*)(w + boff);                    // 12288*256 f16
    _Float16* q_hm    = qin_ctx + (size_t)Q3 * 256;               // 12288*256 f16
    _Float16* qk_ws   = q_hm + (size_t)Q3 * 256;                  // 12288*768 f16
    _Float16* acat    = qk_ws + (size_t)Q3 * 768;                 // 12288*384 f16
    int* allm         = (int*)(acat + (size_t)Q3 * 384);          // 12288 int

    k_init<<<dim3((NN + 255) / 256), dim3(256), 0, stream>>>(lastpos, inv, count);
    k_scatter<<<dim3((MM + 255) / 256), dim3(256), 0, stream>>>(msg_src, lastpos);
    k_compact<<<dim3((NN + 255) / 256), dim3(256), 0, stream>>>(lastpos, inv, comp, count);
    k_cvtw<<<dim3(640), dim3(256), 0, stream>>>(W1, W2, gWi, gWh, Wq, Wv, Wo, mW1, mW2, Wk, Hpool);
    k_stage1<<<dim3((MM + 31) / 32), dim3(256), 0, stream>>>(
        comp, count, lastpos, msg_dst, msg_eidx, msg_t, last_update,
        memory, edge_feats, time_w, time_b,
        W1h, b1, W2h, b2, Wih, Whh, gbi, gbh, new_mem);

    // stage 2
    k2a<<<dim3(Q3 / 32), dim3(256), 0, stream>>>(
        src_nodes, dst_nodes, neg_nodes, inv, new_mem, memory, node_feats, time_b,
        qin_ctx, acat);
    // K2b: q = q_in @ Wq^T + bq
    k_gemm<256, 4, false><<<dim3(Q3 / 32, 1), dim3(256), 0, stream>>>(
        qin_ctx, 256, 0, Wqh, 0, bq, 0, q_hm, 256, 0, nullptr, nullptr);
    // K2c: qk_h = q_h @ Wkt_h  (per head), no bias
    k_gemm<128, 6, false><<<dim3(Q3 / 32, 2), dim3(256), 0, stream>>>(
        q_hm, 256, 128, Wkth, 384 * 128, nullptr, 0, qk_ws, 768, 384, nullptr, nullptr);
    // K2d: attention core (qk -> wsum in place)
    k2d<<<dim3(Q3 / 4), dim3(256), 0, stream>>>(
        neighbors, nb_eidx, nb_et, edge_times, inv, new_mem, memory, node_feats,
        edge_feats, time_w, time_b, bk, q_hm, qk_ws, allm);
    // K2e: ctx_h = wsum_h @ Wv_h^T + bv_h (per head)
    k_gemm<384, 2, false><<<dim3(Q3 / 32, 2), dim3(256), 0, stream>>>(
        qk_ws, 768, 384, Wvh, 128 * 384, bv, 128, qin_ctx, 256, 128, nullptr, nullptr);
    // K2f: attn_out = ctx @ Wo^T + bo, masked rows -> 0, into acat cols 0-255
    k_gemm<256, 4, false><<<dim3(Q3 / 32, 1), dim3(256), 0, stream>>>(
        qin_ctx, 256, 0, Woh, 0, bo, 0, acat, 384, 0, nullptr, allm);
    // K2g: hm = relu(acat @ mW1^T + mb1)
    k_gemm<384, 2, true><<<dim3(Q3 / 32, 1), dim3(256), 0, stream>>>(
        acat, 384, 0, mW1h, 0, mb1, 0, q_hm, 128, 0, nullptr, nullptr);
    // K2h: out = hm @ mW2^T + mb2 (f32 output)
    k_gemm<128, 2, false><<<dim3(Q3 / 32, 1), dim3(256), 0, stream>>>(
        q_hm, 128, 0, mW2h, 0, mb2, 0, nullptr, 128, 0, out, nullptr);
}

// Round 4
// 435.266 us; speedup vs baseline: 5.3478x; 1.3798x over previous
//
#include <hip/hip_runtime.h>
#include <math.h>

#define NN 200000
#define EEDGE 500000
#define BB 4096
#define KK 20
#define MM 100000
#define Q3 (3*BB)

typedef _Float16 __attribute__((ext_vector_type(8))) f16x8;
typedef _Float16 __attribute__((ext_vector_type(4))) f16x4;
typedef float __attribute__((ext_vector_type(4))) f32x4;

#define MFMA16(a,b,c) __builtin_amdgcn_mfma_f32_16x16x32_f16(a,b,c,0,0,0)

// cos(a) for |a| up to ~1e7: f64 range-reduction to revolutions + v_cos_f32.
// (library cosf takes the Payne-Hanek slow path for these args: ~35+ instr)
__device__ __forceinline__ float fast_cos(float a) {
    double ad = (double)a * 0.15915494309189535;   // 1/(2*pi)
    double fr = ad - floor(ad);                    // [0,1) revolutions
    return __builtin_amdgcn_cosf((float)fr);       // cos(2*pi*x)
}

// time encoding matching numpy's f32 arg rounding — NO fma contraction.
__device__ __forceinline__ float tenc(float dt, float w, float b) {
    float p = __fmul_rn(dt, w);
    float a = __fadd_rn(p, b);
    return fast_cos(a);
}

__device__ __forceinline__ float fsigm(float x) {
    return __builtin_amdgcn_rcpf(1.f + __expf(-x));
}
__device__ __forceinline__ float ftanh(float x) {
    return 1.f - 2.f * __builtin_amdgcn_rcpf(1.f + __expf(2.f * x));
}

__device__ __forceinline__ f32x4 z4() {
    f32x4 v; v[0] = 0.f; v[1] = 0.f; v[2] = 0.f; v[3] = 0.f; return v;
}

__global__ void k_init(int* lastpos, int* inv, int* count) {
    int i = blockIdx.x * 256 + threadIdx.x;
    if (i < NN) { lastpos[i] = -1; inv[i] = -1; }
    if (i == 0) *count = 0;
}

__global__ void k_scatter(const int* __restrict__ msg_src, int* __restrict__ lastpos) {
    int i = blockIdx.x * 256 + threadIdx.x;
    if (i < MM) atomicMax(&lastpos[msg_src[i]], i);
}

__global__ void k_compact(const int* __restrict__ lastpos, int* __restrict__ inv,
                          int* __restrict__ comp, int* __restrict__ count) {
    int n = blockIdx.x * 256 + threadIdx.x;
    if (n < NN && lastpos[n] >= 0) {
        int j = atomicAdd(count, 1);
        comp[j] = n;
        inv[n] = j;
    }
}

// convert all weights f32 -> f16 (Wk additionally transposed) into one f16 pool
__global__ void k_cvtw(const float* __restrict__ W1, const float* __restrict__ W2,
                       const float* __restrict__ Wi, const float* __restrict__ Wh,
                       const float* __restrict__ Wq, const float* __restrict__ Wv,
                       const float* __restrict__ Wo, const float* __restrict__ mW1,
                       const float* __restrict__ mW2, const float* __restrict__ Wk,
                       _Float16* __restrict__ dst) {
    int base = (blockIdx.x * 256 + threadIdx.x) * 4;
    #pragma unroll
    for (int u = 0; u < 4; u++) {
        int e = base + u;
        float v;
        if (e < 131072)      v = W1[e];
        else if (e < 163840) v = W2[e - 131072];
        else if (e < 212992) v = Wi[e - 163840];
        else if (e < 262144) v = Wh[e - 212992];
        else if (e < 327680) v = Wq[e - 262144];
        else if (e < 425984) v = Wv[e - 327680];
        else if (e < 491520) v = Wo[e - 425984];
        else if (e < 540672) v = mW1[e - 491520];
        else if (e < 557056) v = mW2[e - 540672];
        else {                               // Wkt[h][c][j] = Wk[h*128+j][c]
            int le = e - 557056;
            int h = le / 49152, rem = le % 49152;
            int c = rem / 128, j = rem % 128;
            v = Wk[(size_t)(h * 128 + j) * 384 + c];
        }
        dst[e] = (_Float16)v;
    }
}

// ---------------- Stage 1 ----------------
__device__ __forceinline__ int SWA(int r, int byteofs) {
    return r * 1024 + (byteofs ^ ((r & 7) << 4));
}

__global__ __launch_bounds__(256, 4)
void k_stage1(const int* __restrict__ comp, const int* __restrict__ count,
              const int* __restrict__ lastpos,
              const int* __restrict__ msg_dst, const int* __restrict__ msg_eidx,
              const int* __restrict__ msg_t, const int* __restrict__ last_update,
              const float* __restrict__ memory, const float* __restrict__ edge_feats,
              const float* __restrict__ time_w, const float* __restrict__ time_b,
              const _Float16* __restrict__ W1h, const float* __restrict__ b1,
              const _Float16* __restrict__ W2h, const float* __restrict__ b2,
              const _Float16* __restrict__ Wih, const _Float16* __restrict__ Whh,
              const float* __restrict__ bi, const float* __restrict__ bh,
              float* __restrict__ new_mem)
{
    __shared__ char rawb[32 * 1024];
    __shared__ int sn[32], sd[32], se[32];
    __shared__ float sdt[32];

    int cnt = *count;
    int r0 = blockIdx.x * 32;
    if (r0 >= cnt) return;
    int tid = threadIdx.x;

    if (tid < 32) {
        int rr = r0 + tid;
        int j = (rr < cnt) ? rr : r0;
        int n = comp[j];
        int idx = lastpos[n];
        sn[tid] = n;
        sd[tid] = msg_dst[idx];
        se[tid] = msg_eidx[idx];
        sdt[tid] = (float)(msg_t[idx] - last_update[n]);
    }
    __syncthreads();

    // data pass: 32 rows x 48 granules (mem[n] | mem[d] | edge), all lanes active
    #pragma unroll
    for (int it = 0; it < 6; it++) {
        int gi = tid + it * 256;
        int r = gi / 48, g = gi - r * 48;
        const float* src;
        if (g < 16)      src = memory + (size_t)sn[r] * 128 + g * 8;
        else if (g < 32) src = memory + (size_t)sd[r] * 128 + (g - 16) * 8;
        else             src = edge_feats + (size_t)se[r] * 128 + (g - 32) * 8;
        float4 a = *(const float4*)src;
        float4 b = *(const float4*)(src + 4);
        f16x8 h;
        h[0] = (_Float16)a.x; h[1] = (_Float16)a.y; h[2] = (_Float16)a.z; h[3] = (_Float16)a.w;
        h[4] = (_Float16)b.x; h[5] = (_Float16)b.y; h[6] = (_Float16)b.z; h[7] = (_Float16)b.w;
        *(f16x8*)(rawb + SWA(r, g * 16)) = h;
    }
    // tenc pass: 32 rows x 16 granules (time enc), all lanes active
    #pragma unroll
    for (int it = 0; it < 2; it++) {
        int gi = tid + it * 256;
        int r = gi >> 4, g = gi & 15;
        int c = g * 8;
        float dt = sdt[r];
        float4 w0 = *(const float4*)(time_w + c);
        float4 w1 = *(const float4*)(time_w + c + 4);
        float4 t0 = *(const float4*)(time_b + c);
        float4 t1 = *(const float4*)(time_b + c + 4);
        f16x8 h;
        h[0] = (_Float16)tenc(dt, w0.x, t0.x); h[1] = (_Float16)tenc(dt, w0.y, t0.y);
        h[2] = (_Float16)tenc(dt, w0.z, t0.z); h[3] = (_Float16)tenc(dt, w0.w, t0.w);
        h[4] = (_Float16)tenc(dt, w1.x, t1.x); h[5] = (_Float16)tenc(dt, w1.y, t1.y);
        h[6] = (_Float16)tenc(dt, w1.z, t1.z); h[7] = (_Float16)tenc(dt, w1.w, t1.w);
        *(f16x8*)(rawb + SWA(r, (48 + g) * 16)) = h;
    }
    __syncthreads();

    int wv = tid >> 6, lane = tid & 63;
    int arow = lane & 15, kg = lane >> 4;

    f32x4 acc1[4][2];
    #pragma unroll
    for (int c = 0; c < 4; c++) { acc1[c][0] = z4(); acc1[c][1] = z4(); }
    for (int ks = 0; ks < 16; ks++) {
        f16x8 a0 = *(const f16x8*)(rawb + SWA(arow,      ks * 64 + kg * 16));
        f16x8 a1 = *(const f16x8*)(rawb + SWA(16 + arow, ks * 64 + kg * 16));
        #pragma unroll
        for (int c = 0; c < 4; c++) {
            int col = (wv * 4 + c) * 16 + arow;
            f16x8 b = *(const f16x8*)(W1h + (size_t)col * 512 + ks * 32 + kg * 8);
            acc1[c][0] = MFMA16(a0, b, acc1[c][0]);
            acc1[c][1] = MFMA16(a1, b, acc1[c][1]);
        }
    }
    __syncthreads();

    #pragma unroll
    for (int c = 0; c < 4; c++) {
        int col = (wv * 4 + c) * 16 + arow;
        float bb = b1[col];
        #pragma unroll
        for (int rt = 0; rt < 2; rt++)
            #pragma unroll
            for (int rg = 0; rg < 4; rg++) {
                int row = rt * 16 + kg * 4 + rg;
                float v = acc1[c][rt][rg] + bb;
                v = fmaxf(v, 0.f);
                *(_Float16*)(rawb + SWA(row, 384 + col * 2)) = (_Float16)v;
            }
    }
    __syncthreads();

    f32x4 acc2[2][2];
    #pragma unroll
    for (int c = 0; c < 2; c++) { acc2[c][0] = z4(); acc2[c][1] = z4(); }
    for (int ks = 0; ks < 8; ks++) {
        f16x8 a0 = *(const f16x8*)(rawb + SWA(arow,      384 + ks * 64 + kg * 16));
        f16x8 a1 = *(const f16x8*)(rawb + SWA(16 + arow, 384 + ks * 64 + kg * 16));
        #pragma unroll
        for (int c = 0; c < 2; c++) {
            int col = (wv * 2 + c) * 16 + arow;
            f16x8 b = *(const f16x8*)(W2h + (size_t)col * 256 + ks * 32 + kg * 8);
            acc2[c][0] = MFMA16(a0, b, acc2[c][0]);
            acc2[c][1] = MFMA16(a1, b, acc2[c][1]);
        }
    }
    __syncthreads();

    #pragma unroll
    for (int c = 0; c < 2; c++) {
        int col = (wv * 2 + c) * 16 + arow;
        float bb = b2[col];
        #pragma unroll
        for (int rt = 0; rt < 2; rt++)
            #pragma unroll
            for (int rg = 0; rg < 4; rg++) {
                int row = rt * 16 + kg * 4 + rg;
                *(_Float16*)(rawb + SWA(row, 384 + col * 2)) =
                    (_Float16)(acc2[c][rt][rg] + bb);
            }
    }
    __syncthreads();

    f32x4 aR[2][2], aZ[2][2], aNi[2][2], aNh[2][2];
    #pragma unroll
    for (int c = 0; c < 2; c++)
        #pragma unroll
        for (int rt = 0; rt < 2; rt++) {
            aR[c][rt] = z4(); aZ[c][rt] = z4(); aNi[c][rt] = z4(); aNh[c][rt] = z4();
        }
    for (int ks = 0; ks < 4; ks++) {
        f16x8 m0 = *(const f16x8*)(rawb + SWA(arow,      384 + ks * 64 + kg * 16));
        f16x8 m1 = *(const f16x8*)(rawb + SWA(16 + arow, 384 + ks * 64 + kg * 16));
        f16x8 h0 = *(const f16x8*)(rawb + SWA(arow,      ks * 64 + kg * 16));
        f16x8 h1v = *(const f16x8*)(rawb + SWA(16 + arow, ks * 64 + kg * 16));
        #pragma unroll
        for (int c = 0; c < 2; c++) {
            int col = (wv * 2 + c) * 16 + arow;
            const _Float16* pi = Wih + (size_t)col * 128 + ks * 32 + kg * 8;
            const _Float16* ph = Whh + (size_t)col * 128 + ks * 32 + kg * 8;
            f16x8 bri = *(const f16x8*)pi;
            f16x8 bzi = *(const f16x8*)(pi + 128 * 128);
            f16x8 bni = *(const f16x8*)(pi + 256 * 128);
            f16x8 brh = *(const f16x8*)ph;
            f16x8 bzh = *(const f16x8*)(ph + 128 * 128);
            f16x8 bnh = *(const f16x8*)(ph + 256 * 128);
            aR[c][0] = MFMA16(m0, bri, aR[c][0]);  aR[c][0] = MFMA16(h0, brh, aR[c][0]);
            aR[c][1] = MFMA16(m1, bri, aR[c][1]);  aR[c][1] = MFMA16(h1v, brh, aR[c][1]);
            aZ[c][0] = MFMA16(m0, bzi, aZ[c][0]);  aZ[c][0] = MFMA16(h0, bzh, aZ[c][0]);
            aZ[c][1] = MFMA16(m1, bzi, aZ[c][1]);  aZ[c][1] = MFMA16(h1v, bzh, aZ[c][1]);
            aNi[c][0] = MFMA16(m0, bni, aNi[c][0]);
            aNi[c][1] = MFMA16(m1, bni, aNi[c][1]);
            aNh[c][0] = MFMA16(h0, bnh, aNh[c][0]);
            aNh[c][1] = MFMA16(h1v, bnh, aNh[c][1]);
        }
    }

    #pragma unroll
    for (int c = 0; c < 2; c++) {
        int col = (wv * 2 + c) * 16 + arow;
        float bir = bi[col],       bhr = bh[col];
        float biz = bi[128 + col], bhz = bh[128 + col];
        float bin_ = bi[256 + col], bhn_ = bh[256 + col];
        #pragma unroll
        for (int rt = 0; rt < 2; rt++)
            #pragma unroll
            for (int rg = 0; rg < 4; rg++) {
                int row = rt * 16 + kg * 4 + rg;
                int rr = r0 + row;
                if (rr < cnt) {
                    float r_ = fsigm(aR[c][rt][rg] + bir + bhr);
                    float zg = fsigm(aZ[c][rt][rg] + biz + bhz);
                    float ng = ftanh(aNi[c][rt][rg] + bin_ + r_ * (aNh[c][rt][rg] + bhn_));
                    float om = memory[(size_t)sn[row] * 128 + col];
                    new_mem[(size_t)rr * 128 + col] = (1.f - zg) * ng + zg * om;
                }
            }
    }
}

// ---------------- Stage 2 ----------------
// k2a: build q_in[12288][256] f16 (sfeat | cos(time_b)) and acat cols 256-383 = sfeat
__global__ void k2a(const int* __restrict__ src_nodes, const int* __restrict__ dst_nodes,
                    const int* __restrict__ neg_nodes, const int* __restrict__ inv,
                    const float* __restrict__ new_mem, const float* __restrict__ memory,
                    const float* __restrict__ node_feats, const float* __restrict__ time_b,
                    _Float16* __restrict__ q_in, _Float16* __restrict__ acat)
{
    __shared__ int snode[32], siv[32];
    int tid = threadIdx.x;
    int r0 = blockIdx.x * 32;
    if (tid < 32) {
        int q = r0 + tid;
        int node = (q < BB) ? src_nodes[q] : (q < 2 * BB) ? dst_nodes[q - BB] : neg_nodes[q - 2 * BB];
        snode[tid] = node;
        siv[tid] = inv[node];
    }
    __syncthreads();
    #pragma unroll
    for (int it = 0; it < 4; it++) {
        int gi = tid + it * 256;
        int r = gi >> 5, ch = gi & 31;
        int c = ch * 4;
        int node = snode[r], iv = siv[r];
        const float* mp = (iv >= 0) ? (new_mem + (size_t)iv * 128) : (memory + (size_t)node * 128);
        float4 mv = *(const float4*)(mp + c);
        float4 nf = *(const float4*)(node_feats + (size_t)node * 128 + c);
        f16x4 sf;
        sf[0] = (_Float16)(mv.x + nf.x); sf[1] = (_Float16)(mv.y + nf.y);
        sf[2] = (_Float16)(mv.z + nf.z); sf[3] = (_Float16)(mv.w + nf.w);
        size_t q = (size_t)(r0 + r);
        *(f16x4*)(q_in + q * 256 + c) = sf;
        *(f16x4*)(acat + q * 384 + 256 + c) = sf;
        float4 tb = *(const float4*)(time_b + c);
        f16x4 te;
        te[0] = (_Float16)fast_cos(tb.x); te[1] = (_Float16)fast_cos(tb.y);
        te[2] = (_Float16)fast_cos(tb.z); te[3] = (_Float16)fast_cos(tb.w);
        *(f16x4*)(q_in + q * 256 + 128 + c) = te;
    }
}

// generic 32-row-tile MFMA GEMM: C[row][coff+cg] = A[row][aoff..aoff+KD) . B[cg][0..KD) + bias
template<int KD, int NFRAG, bool RELU>
__global__ __launch_bounds__(256, 2)
void k_gemm(const _Float16* __restrict__ A, int lda, int a_ys,
            const _Float16* __restrict__ B, int b_ys,
            const float* __restrict__ bias, int bias_ys,
            _Float16* __restrict__ C, int ldc, int c_ys,
            float* __restrict__ C32,
            const int* __restrict__ rowmask)
{
    constexpr int ROWB = KD * 2;
    __shared__ char As[32 * ROWB];
    int tid = threadIdx.x;
    int r0 = blockIdx.x * 32;
    int aoff = blockIdx.y * a_ys;
    const _Float16* Bp = B + (size_t)blockIdx.y * b_ys;
    int coff = blockIdx.y * c_ys;

    #pragma unroll
    for (int t = 0; t < (32 * KD / 8) / 256; t++) {
        int gi = tid + t * 256;
        int r = gi / (KD / 8), g = gi % (KD / 8);
        f16x8 v = *(const f16x8*)(A + (size_t)(r0 + r) * lda + aoff + g * 8);
        *(f16x8*)(&As[r * ROWB + ((g * 16) ^ ((r & 7) << 4))]) = v;
    }
    __syncthreads();

    int wv = tid >> 6, lane = tid & 63;
    int arow = lane & 15, kg = lane >> 4;
    f32x4 acc[NFRAG][2];
    #pragma unroll
    for (int c = 0; c < NFRAG; c++) { acc[c][0] = z4(); acc[c][1] = z4(); }

    #pragma unroll
    for (int ks = 0; ks < KD / 32; ks++) {
        f16x8 a0 = *(const f16x8*)(&As[arow * ROWB + ((ks * 64 + kg * 16) ^ ((arow & 7) << 4))]);
        f16x8 a1 = *(const f16x8*)(&As[(16 + arow) * ROWB + ((ks * 64 + kg * 16) ^ ((arow & 7) << 4))]);
        #pragma unroll
        for (int c = 0; c < NFRAG; c++) {
            int cg = (wv * NFRAG + c) * 16 + arow;
            f16x8 b = *(const f16x8*)(Bp + (size_t)cg * KD + ks * 32 + kg * 8);
            acc[c][0] = MFMA16(a0, b, acc[c][0]);
            acc[c][1] = MFMA16(a1, b, acc[c][1]);
        }
    }

    #pragma unroll
    for (int c = 0; c < NFRAG; c++) {
        int cg = (wv * NFRAG + c) * 16 + arow;
        float bb = bias ? bias[blockIdx.y * bias_ys + cg] : 0.f;
        #pragma unroll
        for (int rt = 0; rt < 2; rt++)
            #pragma unroll
            for (int rg = 0; rg < 4; rg++) {
                int grow = r0 + rt * 16 + kg * 4 + rg;
                float v = acc[c][rt][rg] + bb;
                if (RELU) v = fmaxf(v, 0.f);
                if (rowmask && rowmask[grow]) v = 0.f;
                if (C)   C[(size_t)grow * ldc + coff + cg] = (_Float16)v;
                if (C32) C32[(size_t)grow * ldc + coff + cg] = v;
            }
    }
}

// k2d: attention core. 1 query per wave, head per half-wave, no LDS, no barriers.
// Depth-1 software pipeline on the neighbor gathers.
__global__ __launch_bounds__(256)
void k2d(const int* __restrict__ neighbors, const int* __restrict__ nb_eidx,
         const int* __restrict__ nb_et, const int* __restrict__ edge_times,
         const int* __restrict__ inv, const float* __restrict__ new_mem,
         const float* __restrict__ memory, const float* __restrict__ node_feats,
         const float* __restrict__ edge_feats, const float* __restrict__ time_w,
         const float* __restrict__ time_b, const float* __restrict__ bk,
         const _Float16* __restrict__ qbuf, _Float16* __restrict__ qk_wsum,
         int* __restrict__ allm)
{
    int tid = threadIdx.x;
    int qi = blockIdx.x * 4 + (tid >> 6);
    int lane = tid & 63;
    int h = lane >> 5, l32 = lane & 31;
    int c0 = l32 * 4;

    float4 tw = *(const float4*)(time_w + c0);
    float4 tb = *(const float4*)(time_b + c0);

    const _Float16* qkp = qk_wsum + (size_t)qi * 768 + h * 384;
    f16x4 t0 = *(const f16x4*)(qkp + c0);
    f16x4 t1 = *(const f16x4*)(qkp + 128 + c0);
    f16x4 t2 = *(const f16x4*)(qkp + 256 + c0);
    float qk0[4], qk1[4], qk2[4];
    #pragma unroll
    for (int t = 0; t < 4; t++) { qk0[t] = (float)t0[t]; qk1[t] = (float)t1[t]; qk2[t] = (float)t2[t]; }

    // cb = q_h . bk_h
    f16x4 qv = *(const f16x4*)(qbuf + (size_t)qi * 256 + h * 128 + c0);
    float4 bkv = *(const float4*)(bk + h * 128 + c0);
    float cb = (float)qv[0] * bkv.x + (float)qv[1] * bkv.y +
               (float)qv[2] * bkv.z + (float)qv[3] * bkv.w;
    cb += __shfl_xor(cb, 1, 32);
    cb += __shfl_xor(cb, 2, 32);
    cb += __shfl_xor(cb, 4, 32);
    cb += __shfl_xor(cb, 8, 32);
    cb += __shfl_xor(cb, 16, 32);

    float ts = (float)edge_times[qi & (BB - 1)];
    float m_run = -3.0e38f, l_run = 0.f;
    float w0[4] = {0,0,0,0}, w1[4] = {0,0,0,0}, w2[4] = {0,0,0,0};
    int anyv = 0;
    const float inv_sqrt = 0.08838834764831845f;

    int base = qi * KK;
    // prefetch j=0
    int nb_c = neighbors[base];
    int ei_c = nb_eidx[base];
    int et_c = nb_et[base];
    float4 mv, nf, ef;
    {
        int iv = inv[nb_c];
        const float* mp = (iv >= 0) ? (new_mem + (size_t)iv * 128) : (memory + (size_t)nb_c * 128);
        mv = *(const float4*)(mp + c0);
        nf = *(const float4*)(node_feats + (size_t)nb_c * 128 + c0);
        ef = *(const float4*)(edge_feats + (size_t)ei_c * 128 + c0);
    }

    for (int j = 0; j < KK; j++) {
        int nb_n = 0, ei_n = 0, et_n = 0;
        float4 mv_n = {0,0,0,0}, nf_n = {0,0,0,0}, ef_n = {0,0,0,0};
        if (j + 1 < KK) {
            nb_n = neighbors[base + j + 1];
            ei_n = nb_eidx[base + j + 1];
            et_n = nb_et[base + j + 1];
            int iv = inv[nb_n];
            const float* mp = (iv >= 0) ? (new_mem + (size_t)iv * 128) : (memory + (size_t)nb_n * 128);
            mv_n = *(const float4*)(mp + c0);
            nf_n = *(const float4*)(node_feats + (size_t)nb_n * 128 + c0);
            ef_n = *(const float4*)(edge_feats + (size_t)ei_n * 128 + c0);
        }

        float dtf = ts - (float)et_c;
        anyv |= (nb_c != 0);
        float k0[4] = { mv.x + nf.x, mv.y + nf.y, mv.z + nf.z, mv.w + nf.w };
        float k1[4] = { tenc(dtf, tw.x, tb.x), tenc(dtf, tw.y, tb.y),
                        tenc(dtf, tw.z, tb.z), tenc(dtf, tw.w, tb.w) };
        float k2[4] = { ef.x, ef.y, ef.z, ef.w };

        float sp = 0.f;
        #pragma unroll
        for (int t = 0; t < 4; t++)
            sp += qk0[t] * k0[t] + qk1[t] * k1[t] + qk2[t] * k2[t];
        sp += __shfl_xor(sp, 1, 32);
        sp += __shfl_xor(sp, 2, 32);
        sp += __shfl_xor(sp, 4, 32);
        sp += __shfl_xor(sp, 8, 32);
        sp += __shfl_xor(sp, 16, 32);

        float s = (sp + cb) * inv_sqrt;
        if (nb_c == 0) s = -1e9f;
        float m_new = fmaxf(m_run, s);
        float sc = __expf(m_run - m_new);
        float p = __expf(s - m_new);
        l_run = l_run * sc + p;
        #pragma unroll
        for (int t = 0; t < 4; t++) {
            w0[t] = w0[t] * sc + p * k0[t];
            w1[t] = w1[t] * sc + p * k1[t];
            w2[t] = w2[t] * sc + p * k2[t];
        }
        m_run = m_new;

        nb_c = nb_n; ei_c = ei_n; et_c = et_n;
        mv = mv_n; nf = nf_n; ef = ef_n;
    }

    float linv = __builtin_amdgcn_rcpf(l_run);
    _Float16* wp = qk_wsum + (size_t)qi * 768 + h * 384;   // overwrite qk (fully consumed)
    f16x4 o0, o1, o2;
    #pragma unroll
    for (int t = 0; t < 4; t++) {
        o0[t] = (_Float16)(w0[t] * linv);
        o1[t] = (_Float16)(w1[t] * linv);
        o2[t] = (_Float16)(w2[t] * linv);
    }
    *(f16x4*)(wp + c0) = o0;
    *(f16x4*)(wp + 128 + c0) = o1;
    *(f16x4*)(wp + 256 + c0) = o2;
    if (lane == 0) allm[qi] = anyv ? 0 : 1;
}

extern "C" void kernel_launch(void* const* d_in, const int* in_sizes, int n_in,
                              void* d_out, int out_size, void* d_ws, size_t ws_size,
                              hipStream_t stream) {
    (void)in_sizes; (void)n_in; (void)out_size; (void)ws_size;
    const int* src_nodes  = (const int*)d_in[0];
    const int* dst_nodes  = (const int*)d_in[1];
    const int* neg_nodes  = (const int*)d_in[2];
    const int* edge_times = (const int*)d_in[3];
    const int* neighbors  = (const int*)d_in[4];
    const int* nb_eidx    = (const int*)d_in[5];
    const int* nb_et      = (const int*)d_in[6];
    const int* msg_src    = (const int*)d_in[7];
    const int* msg_dst    = (const int*)d_in[8];
    const int* msg_eidx   = (const int*)d_in[9];
    const int* msg_t      = (const int*)d_in[10];
    const int* last_update= (const int*)d_in[11];
    const float* node_feats = (const float*)d_in[12];
    const float* edge_feats = (const float*)d_in[13];
    const float* memory     = (const float*)d_in[14];
    const float* time_w = (const float*)d_in[15];
    const float* time_b = (const float*)d_in[16];
    const float* W1 = (const float*)d_in[17];
    const float* b1 = (const float*)d_in[18];
    const float* W2 = (const float*)d_in[19];
    const float* b2 = (const float*)d_in[20];
    const float* gWi = (const float*)d_in[21];
    const float* gWh = (const float*)d_in[22];
    const float* gbi = (const float*)d_in[23];
    const float* gbh = (const float*)d_in[24];
    const float* Wq = (const float*)d_in[25];
    const float* bq = (const float*)d_in[26];
    const float* Wk = (const float*)d_in[27];
    const float* bk = (const float*)d_in[28];
    const float* Wv = (const float*)d_in[29];
    const float* bv = (const float*)d_in[30];
    const float* Wo = (const float*)d_in[31];
    const float* bo = (const float*)d_in[32];
    const float* mW1 = (const float*)d_in[33];
    const float* mb1 = (const float*)d_in[34];
    const float* mW2 = (const float*)d_in[35];
    const float* mb2 = (const float*)d_in[36];
    float* out = (float*)d_out;

    char* w = (char*)d_ws;
    int* lastpos = (int*)w;
    int* inv  = lastpos + NN;
    int* comp = inv + NN;
    int* count = comp + NN;
    size_t off = ((size_t)(3 * NN + 1) * 4 + 255) & ~(size_t)255;
    float* new_mem = (float*)(w + off);               // MM*128 f32 (51.2 MB)
    size_t woff = off + (size_t)MM * 128 * 4;

    _Float16* Hpool = (_Float16*)(w + woff);          // 655360 f16 weights
    _Float16* W1h  = Hpool;
    _Float16* W2h  = Hpool + 131072;
    _Float16* Wih  = Hpool + 163840;
    _Float16* Whh  = Hpool + 212992;
    _Float16* Wqh  = Hpool + 262144;
    _Float16* Wvh  = Hpool + 327680;
    _Float16* Woh  = Hpool + 425984;
    _Float16* mW1h = Hpool + 491520;
    _Float16* mW2h = Hpool + 540672;
    _Float16* Wkth = Hpool + 557056;
    size_t boff = woff + (size_t)655360 * 2;

    _Float16* qin_ctx = (_Float16*)(w + boff);                    // 12288*256 f16
    _Float16* q_hm    = qin_ctx + (size_t)Q3 * 256;               // 12288*256 f16
    _Float16* qk_ws   = q_hm + (size_t)Q3 * 256;                  // 12288*768 f16
    _Float16* acat    = qk_ws + (size_t)Q3 * 768;                 // 12288*384 f16
    int* allm         = (int*)(acat + (size_t)Q3 * 384);          // 12288 int

    k_init<<<dim3((NN + 255) / 256), dim3(256), 0, stream>>>(lastpos, inv, count);
    k_scatter<<<dim3((MM + 255) / 256), dim3(256), 0, stream>>>(msg_src, lastpos);
    k_compact<<<dim3((NN + 255) / 256), dim3(256), 0, stream>>>(lastpos, inv, comp, count);
    k_cvtw<<<dim3(640), dim3(256), 0, stream>>>(W1, W2, gWi, gWh, Wq, Wv, Wo, mW1, mW2, Wk, Hpool);
    k_stage1<<<dim3((MM + 31) / 32), dim3(256), 0, stream>>>(
        comp, count, lastpos, msg_dst, msg_eidx, msg_t, last_update,
        memory, edge_feats, time_w, time_b,
        W1h, b1, W2h, b2, Wih, Whh, gbi, gbh, new_mem);

    // stage 2
    k2a<<<dim3(Q3 / 32), dim3(256), 0, stream>>>(
        src_nodes, dst_nodes, neg_nodes, inv, new_mem, memory, node_feats, time_b,
        qin_ctx, acat);
    // K2b: q = q_in @ Wq^T + bq
    k_gemm<256, 4, false><<<dim3(Q3 / 32, 1), dim3(256), 0, stream>>>(
        qin_ctx, 256, 0, Wqh, 0, bq, 0, q_hm, 256, 0, nullptr, nullptr);
    // K2c: qk_h = q_h @ Wkt_h  (per head), no bias
    k_gemm<128, 6, false><<<dim3(Q3 / 32, 2), dim3(256), 0, stream>>>(
        q_hm, 256, 128, Wkth, 384 * 128, nullptr, 0, qk_ws, 768, 384, nullptr, nullptr);
    // K2d: attention core (qk -> wsum in place)
    k2d<<<dim3(Q3 / 4), dim3(256), 0, stream>>>(
        neighbors, nb_eidx, nb_et, edge_times, inv, new_mem, memory, node_feats,
        edge_feats, time_w, time_b, bk, q_hm, qk_ws, allm);
    // K2e: ctx_h = wsum_h @ Wv_h^T + bv_h (per head)
    k_gemm<384, 2, false><<<dim3(Q3 / 32, 2), dim3(256), 0, stream>>>(
        qk_ws, 768, 384, Wvh, 128 * 384, bv, 128, qin_ctx, 256, 128, nullptr, nullptr);
    // K2f: attn_out = ctx @ Wo^T + bo, masked rows -> 0, into acat cols 0-255
    k_gemm<256, 4, false><<<dim3(Q3 / 32, 1), dim3(256), 0, stream>>>(
        qin_ctx, 256, 0, Woh, 0, bo, 0, acat, 384, 0, nullptr, allm);
    // K2g: hm = relu(acat @ mW1^T + mb1)
    k_gemm<384, 2, true><<<dim3(Q3 / 32, 1), dim3(256), 0, stream>>>(
        acat, 384, 0, mW1h, 0, mb1, 0, q_hm, 128, 0, nullptr, nullptr);
    // K2h: out = hm @ mW2^T + mb2 (f32 output)
    k_gemm<128, 2, false><<<dim3(Q3 / 32, 1), dim3(256), 0, stream>>>(
        q_hm, 128, 0, mW2h, 0, mb2, 0, nullptr, 128, 0, out, nullptr);
}

// Round 5
// 389.211 us; speedup vs baseline: 5.9806x; 1.1183x over previous
//
#include <hip/hip_runtime.h>
#include <math.h>

#define NN 200000
#define EEDGE 500000
#define BB 4096
#define KK 20
#define MM 100000
#define Q3 (3*BB)

typedef _Float16 __attribute__((ext_vector_type(8))) f16x8;
typedef _Float16 __attribute__((ext_vector_type(4))) f16x4;
typedef float __attribute__((ext_vector_type(4))) f32x4;

#define MFMA16(a,b,c) __builtin_amdgcn_mfma_f32_16x16x32_f16(a,b,c,0,0,0)

// cos(a) for |a| up to ~1e7: f64 range-reduction to revolutions + v_cos_f32.
__device__ __forceinline__ float fast_cos(float a) {
    double ad = (double)a * 0.15915494309189535;   // 1/(2*pi)
    double fr = ad - floor(ad);                    // [0,1) revolutions
    return __builtin_amdgcn_cosf((float)fr);       // cos(2*pi*x)
}

// time encoding matching numpy's f32 arg rounding — NO fma contraction.
__device__ __forceinline__ float tenc(float dt, float w, float b) {
    float p = __fmul_rn(dt, w);
    float a = __fadd_rn(p, b);
    return fast_cos(a);
}

__device__ __forceinline__ float fsigm(float x) {
    return __builtin_amdgcn_rcpf(1.f + __expf(-x));
}
__device__ __forceinline__ float ftanh(float x) {
    return 1.f - 2.f * __builtin_amdgcn_rcpf(1.f + __expf(2.f * x));
}

__device__ __forceinline__ f32x4 z4() {
    f32x4 v; v[0] = 0.f; v[1] = 0.f; v[2] = 0.f; v[3] = 0.f; return v;
}

__global__ void k_init(int* lastpos, int* inv, int* count) {
    int i = blockIdx.x * 256 + threadIdx.x;
    if (i < NN) { lastpos[i] = -1; inv[i] = -1; }
    if (i == 0) *count = 0;
}

__global__ void k_scatter(const int* __restrict__ msg_src, int* __restrict__ lastpos) {
    int i = blockIdx.x * 256 + threadIdx.x;
    if (i < MM) atomicMax(&lastpos[msg_src[i]], i);
}

__global__ void k_compact(const int* __restrict__ lastpos, int* __restrict__ inv,
                          int* __restrict__ comp, int* __restrict__ count) {
    int n = blockIdx.x * 256 + threadIdx.x;
    if (n < NN && lastpos[n] >= 0) {
        int j = atomicAdd(count, 1);
        comp[j] = n;
        inv[n] = j;
    }
}

// f32 -> f16 weight conversion into MFMA FRAGMENT ORDER:
// elem offset = matbase + ((cgrp*KS + ks)*64 + lane)*8 + e
//   lane = kg*16 + arow; col = cgrp*16 + arow; k = ks*32 + kg*8 + e
// Every wave B-load becomes one contiguous 1KB coalesced read.
__global__ void k_cvtw(const float* __restrict__ W1, const float* __restrict__ W2,
                       const float* __restrict__ Wi, const float* __restrict__ Wh,
                       const float* __restrict__ Wq, const float* __restrict__ Wv,
                       const float* __restrict__ Wo, const float* __restrict__ mW1,
                       const float* __restrict__ mW2, const float* __restrict__ Wk,
                       _Float16* __restrict__ dst) {
    int f = blockIdx.x * 256 + threadIdx.x;   // fragment id, 81920 total
    if (f >= 81920) return;
    const float* src; int dstoff, K, lf, tr = -1;
    if      (f < 16384) { src = W1;  dstoff = 0;      K = 512; lf = f; }
    else if (f < 20480) { src = W2;  dstoff = 131072; K = 256; lf = f - 16384; }
    else if (f < 26624) { src = Wi;  dstoff = 163840; K = 128; lf = f - 20480; }
    else if (f < 32768) { src = Wh;  dstoff = 212992; K = 128; lf = f - 26624; }
    else if (f < 40960) { src = Wq;  dstoff = 262144; K = 256; lf = f - 32768; }
    else if (f < 47104) { src = Wv;  dstoff = 327680; K = 384; lf = f - 40960; }
    else if (f < 53248) { src = Wv + 128 * 384; dstoff = 376832; K = 384; lf = f - 47104; }
    else if (f < 61440) { src = Wo;  dstoff = 425984; K = 256; lf = f - 53248; }
    else if (f < 67584) { src = mW1; dstoff = 491520; K = 384; lf = f - 61440; }
    else if (f < 69632) { src = mW2; dstoff = 540672; K = 128; lf = f - 67584; }
    else if (f < 75776) { src = Wk;  dstoff = 557056; K = 128; lf = f - 69632; tr = 0; }
    else                { src = Wk;  dstoff = 606208; K = 128; lf = f - 75776; tr = 1; }
    int KS = K >> 5;
    int cgrp = lf / (KS * 64);
    int rem  = lf - cgrp * (KS * 64);
    int ks = rem >> 6, lane = rem & 63;
    int kg = lane >> 4, arow = lane & 15;
    int col = cgrp * 16 + arow;
    int k0 = ks * 32 + kg * 8;
    f16x8 h;
    if (tr < 0) {
        const float* p = src + (size_t)col * K + k0;
        float4 a = *(const float4*)p;
        float4 b = *(const float4*)(p + 4);
        h[0] = (_Float16)a.x; h[1] = (_Float16)a.y; h[2] = (_Float16)a.z; h[3] = (_Float16)a.w;
        h[4] = (_Float16)b.x; h[5] = (_Float16)b.y; h[6] = (_Float16)b.z; h[7] = (_Float16)b.w;
    } else {
        // qk-fold: B[col=j][k=c] = Wk[(h*128+k)*384 + j]
        #pragma unroll
        for (int e = 0; e < 8; e++)
            h[e] = (_Float16)Wk[(size_t)(tr * 128 + k0 + e) * 384 + col];
    }
    *(f16x8*)(dst + dstoff + (size_t)lf * 8) = h;
}

// ---------------- Stage 1: 512 threads / 8 waves / 32 rows ----------------
__device__ __forceinline__ int SWA(int r, int byteofs) {
    return r * 1024 + (byteofs ^ ((r & 7) << 4));
}

// fragment-order weight load, K=128 (KS=4)
__device__ __forceinline__ f16x8 ldw4(const _Float16* W, int cg, int ks, int lane) {
    return *(const f16x8*)(W + (((size_t)cg * 4 + ks) * 64 + lane) * 8);
}

__global__ __launch_bounds__(512, 8)
void k_stage1(const int* __restrict__ comp, const int* __restrict__ count,
              const int* __restrict__ lastpos,
              const int* __restrict__ msg_dst, const int* __restrict__ msg_eidx,
              const int* __restrict__ msg_t, const int* __restrict__ last_update,
              const float* __restrict__ memory, const float* __restrict__ edge_feats,
              const float* __restrict__ time_w, const float* __restrict__ time_b,
              const _Float16* __restrict__ W1h, const float* __restrict__ b1,
              const _Float16* __restrict__ W2h, const float* __restrict__ b2,
              const _Float16* __restrict__ Wih, const _Float16* __restrict__ Whh,
              const float* __restrict__ bi, const float* __restrict__ bh,
              float* __restrict__ new_mem)
{
    __shared__ char rawb[32 * 1024];
    __shared__ int sn[32], sd[32], se[32];
    __shared__ float sdt[32];

    int cnt = *count;
    int r0 = blockIdx.x * 32;
    if (r0 >= cnt) return;
    int tid = threadIdx.x;

    if (tid < 32) {
        int rr = r0 + tid;
        int j = (rr < cnt) ? rr : r0;
        int n = comp[j];
        int idx = lastpos[n];
        sn[tid] = n;
        sd[tid] = msg_dst[idx];
        se[tid] = msg_eidx[idx];
        sdt[tid] = (float)(msg_t[idx] - last_update[n]);
    }
    __syncthreads();

    // data pass: 32 rows x 48 granules (mem[n] | mem[d] | edge)
    #pragma unroll
    for (int it = 0; it < 3; it++) {
        int gi = tid + it * 512;
        int r = gi / 48, g = gi - r * 48;
        const float* src;
        if (g < 16)      src = memory + (size_t)sn[r] * 128 + g * 8;
        else if (g < 32) src = memory + (size_t)sd[r] * 128 + (g - 16) * 8;
        else             src = edge_feats + (size_t)se[r] * 128 + (g - 32) * 8;
        float4 a = *(const float4*)src;
        float4 b = *(const float4*)(src + 4);
        f16x8 h;
        h[0] = (_Float16)a.x; h[1] = (_Float16)a.y; h[2] = (_Float16)a.z; h[3] = (_Float16)a.w;
        h[4] = (_Float16)b.x; h[5] = (_Float16)b.y; h[6] = (_Float16)b.z; h[7] = (_Float16)b.w;
        *(f16x8*)(rawb + SWA(r, g * 16)) = h;
    }
    // tenc pass: 32 rows x 16 granules
    {
        int r = tid >> 4, g = tid & 15;
        int c = g * 8;
        float dt = sdt[r];
        float4 w0 = *(const float4*)(time_w + c);
        float4 w1 = *(const float4*)(time_w + c + 4);
        float4 t0 = *(const float4*)(time_b + c);
        float4 t1 = *(const float4*)(time_b + c + 4);
        f16x8 h;
        h[0] = (_Float16)tenc(dt, w0.x, t0.x); h[1] = (_Float16)tenc(dt, w0.y, t0.y);
        h[2] = (_Float16)tenc(dt, w0.z, t0.z); h[3] = (_Float16)tenc(dt, w0.w, t0.w);
        h[4] = (_Float16)tenc(dt, w1.x, t1.x); h[5] = (_Float16)tenc(dt, w1.y, t1.y);
        h[6] = (_Float16)tenc(dt, w1.z, t1.z); h[7] = (_Float16)tenc(dt, w1.w, t1.w);
        *(f16x8*)(rawb + SWA(r, (48 + g) * 16)) = h;
    }
    __syncthreads();

    int wv = tid >> 6, lane = tid & 63;
    int arow = lane & 15, kg = lane >> 4;

    // GEMM1: h1[32][256], K=512; wave owns col-groups {2wv, 2wv+1}
    f32x4 acc1[2][2];
    #pragma unroll
    for (int c = 0; c < 2; c++) { acc1[c][0] = z4(); acc1[c][1] = z4(); }
    for (int ks = 0; ks < 16; ks++) {
        f16x8 a0 = *(const f16x8*)(rawb + SWA(arow,      ks * 64 + kg * 16));
        f16x8 a1 = *(const f16x8*)(rawb + SWA(16 + arow, ks * 64 + kg * 16));
        #pragma unroll
        for (int c = 0; c < 2; c++) {
            f16x8 b = *(const f16x8*)(W1h + (((size_t)(wv * 2 + c) * 16 + ks) * 64 + lane) * 8);
            acc1[c][0] = MFMA16(a0, b, acc1[c][0]);
            acc1[c][1] = MFMA16(a1, b, acc1[c][1]);
        }
    }
    __syncthreads();

    #pragma unroll
    for (int c = 0; c < 2; c++) {
        int col = (wv * 2 + c) * 16 + arow;
        float bb = b1[col];
        #pragma unroll
        for (int rt = 0; rt < 2; rt++)
            #pragma unroll
            for (int rg = 0; rg < 4; rg++) {
                int row = rt * 16 + kg * 4 + rg;
                float v = fmaxf(acc1[c][rt][rg] + bb, 0.f);
                *(_Float16*)(rawb + SWA(row, 384 + col * 2)) = (_Float16)v;
            }
    }
    __syncthreads();

    // GEMM2: msg[32][128], K=256; wave owns col-group wv
    f32x4 acc2[2];
    acc2[0] = z4(); acc2[1] = z4();
    for (int ks = 0; ks < 8; ks++) {
        f16x8 a0 = *(const f16x8*)(rawb + SWA(arow,      384 + ks * 64 + kg * 16));
        f16x8 a1 = *(const f16x8*)(rawb + SWA(16 + arow, 384 + ks * 64 + kg * 16));
        f16x8 b = *(const f16x8*)(W2h + (((size_t)wv * 8 + ks) * 64 + lane) * 8);
        acc2[0] = MFMA16(a0, b, acc2[0]);
        acc2[1] = MFMA16(a1, b, acc2[1]);
    }
    __syncthreads();

    {
        int col = wv * 16 + arow;
        float bb = b2[col];
        #pragma unroll
        for (int rt = 0; rt < 2; rt++)
            #pragma unroll
            for (int rg = 0; rg < 4; rg++) {
                int row = rt * 16 + kg * 4 + rg;
                *(_Float16*)(rawb + SWA(row, 384 + col * 2)) =
                    (_Float16)(acc2[rt][rg] + bb);
            }
    }
    __syncthreads();

    // GRU gates: wave owns gate col-group wv (cols wv*16+arow of each gate)
    f32x4 aR[2], aZ[2], aNi[2], aNh[2];
    aR[0] = z4(); aR[1] = z4(); aZ[0] = z4(); aZ[1] = z4();
    aNi[0] = z4(); aNi[1] = z4(); aNh[0] = z4(); aNh[1] = z4();
    for (int ks = 0; ks < 4; ks++) {
        f16x8 m0 = *(const f16x8*)(rawb + SWA(arow,      384 + ks * 64 + kg * 16));
        f16x8 m1 = *(const f16x8*)(rawb + SWA(16 + arow, 384 + ks * 64 + kg * 16));
        f16x8 h0 = *(const f16x8*)(rawb + SWA(arow,      ks * 64 + kg * 16));
        f16x8 h1 = *(const f16x8*)(rawb + SWA(16 + arow, ks * 64 + kg * 16));
        {   // r gate
            f16x8 bi_ = ldw4(Wih, wv, ks, lane);
            f16x8 bh_ = ldw4(Whh, wv, ks, lane);
            aR[0] = MFMA16(m0, bi_, aR[0]); aR[0] = MFMA16(h0, bh_, aR[0]);
            aR[1] = MFMA16(m1, bi_, aR[1]); aR[1] = MFMA16(h1, bh_, aR[1]);
        }
        {   // z gate
            f16x8 bi_ = ldw4(Wih, 8 + wv, ks, lane);
            f16x8 bh_ = ldw4(Whh, 8 + wv, ks, lane);
            aZ[0] = MFMA16(m0, bi_, aZ[0]); aZ[0] = MFMA16(h0, bh_, aZ[0]);
            aZ[1] = MFMA16(m1, bi_, aZ[1]); aZ[1] = MFMA16(h1, bh_, aZ[1]);
        }
        {   // n gates (kept separate for r*(...) )
            f16x8 bi_ = ldw4(Wih, 16 + wv, ks, lane);
            f16x8 bh_ = ldw4(Whh, 16 + wv, ks, lane);
            aNi[0] = MFMA16(m0, bi_, aNi[0]); aNi[1] = MFMA16(m1, bi_, aNi[1]);
            aNh[0] = MFMA16(h0, bh_, aNh[0]); aNh[1] = MFMA16(h1, bh_, aNh[1]);
        }
    }

    {
        int col = wv * 16 + arow;
        float bir = bi[col],        bhr = bh[col];
        float biz = bi[128 + col],  bhz = bh[128 + col];
        float bin_ = bi[256 + col], bhn_ = bh[256 + col];
        #pragma unroll
        for (int rt = 0; rt < 2; rt++)
            #pragma unroll
            for (int rg = 0; rg < 4; rg++) {
                int row = rt * 16 + kg * 4 + rg;
                int rr = r0 + row;
                if (rr < cnt) {
                    float r_ = fsigm(aR[rt][rg] + bir + bhr);
                    float zg = fsigm(aZ[rt][rg] + biz + bhz);
                    float ng = ftanh(aNi[rt][rg] + bin_ + r_ * (aNh[rt][rg] + bhn_));
                    // old memory from LDS (f16-rounded; |err| ~7e-5 in z*om)
                    float om = (float)*(const _Float16*)(rawb + SWA(row, col * 2));
                    new_mem[(size_t)rr * 128 + col] = (1.f - zg) * ng + zg * om;
                }
            }
    }
}

// ---------------- Stage 2 ----------------
__global__ void k2a(const int* __restrict__ src_nodes, const int* __restrict__ dst_nodes,
                    const int* __restrict__ neg_nodes, const int* __restrict__ inv,
                    const float* __restrict__ new_mem, const float* __restrict__ memory,
                    const float* __restrict__ node_feats, const float* __restrict__ time_b,
                    _Float16* __restrict__ q_in, _Float16* __restrict__ acat)
{
    __shared__ int snode[32], siv[32];
    int tid = threadIdx.x;
    int r0 = blockIdx.x * 32;
    if (tid < 32) {
        int q = r0 + tid;
        int node = (q < BB) ? src_nodes[q] : (q < 2 * BB) ? dst_nodes[q - BB] : neg_nodes[q - 2 * BB];
        snode[tid] = node;
        siv[tid] = inv[node];
    }
    __syncthreads();
    #pragma unroll
    for (int it = 0; it < 4; it++) {
        int gi = tid + it * 256;
        int r = gi >> 5, ch = gi & 31;
        int c = ch * 4;
        int node = snode[r], iv = siv[r];
        const float* mp = (iv >= 0) ? (new_mem + (size_t)iv * 128) : (memory + (size_t)node * 128);
        float4 mv = *(const float4*)(mp + c);
        float4 nf = *(const float4*)(node_feats + (size_t)node * 128 + c);
        f16x4 sf;
        sf[0] = (_Float16)(mv.x + nf.x); sf[1] = (_Float16)(mv.y + nf.y);
        sf[2] = (_Float16)(mv.z + nf.z); sf[3] = (_Float16)(mv.w + nf.w);
        size_t q = (size_t)(r0 + r);
        *(f16x4*)(q_in + q * 256 + c) = sf;
        *(f16x4*)(acat + q * 384 + 256 + c) = sf;
        float4 tb = *(const float4*)(time_b + c);
        f16x4 te;
        te[0] = (_Float16)fast_cos(tb.x); te[1] = (_Float16)fast_cos(tb.y);
        te[2] = (_Float16)fast_cos(tb.z); te[3] = (_Float16)fast_cos(tb.w);
        *(f16x4*)(q_in + q * 256 + 128 + c) = te;
    }
}

// generic 32-row-tile MFMA GEMM, fragment-ordered B.
template<int KD, int NFRAG, bool RELU>
__global__ __launch_bounds__(256, 4)
void k_gemm(const _Float16* __restrict__ A, int lda, int a_ys,
            const _Float16* __restrict__ B, int b_ys,
            const float* __restrict__ bias, int bias_ys,
            _Float16* __restrict__ C, int ldc, int c_ys,
            float* __restrict__ C32,
            const int* __restrict__ rowmask)
{
    constexpr int ROWB = KD * 2;
    __shared__ char As[32 * ROWB];
    int tid = threadIdx.x;
    int r0 = blockIdx.x * 32;
    int aoff = blockIdx.y * a_ys;
    const _Float16* Bp = B + (size_t)blockIdx.y * b_ys;
    int coff = blockIdx.y * c_ys;

    #pragma unroll
    for (int t = 0; t < (32 * KD / 8) / 256; t++) {
        int gi = tid + t * 256;
        int r = gi / (KD / 8), g = gi % (KD / 8);
        f16x8 v = *(const f16x8*)(A + (size_t)(r0 + r) * lda + aoff + g * 8);
        *(f16x8*)(&As[r * ROWB + ((g * 16) ^ ((r & 7) << 4))]) = v;
    }
    __syncthreads();

    int wv = tid >> 6, lane = tid & 63;
    int arow = lane & 15, kg = lane >> 4;
    f32x4 acc[NFRAG][2];
    #pragma unroll
    for (int c = 0; c < NFRAG; c++) { acc[c][0] = z4(); acc[c][1] = z4(); }

    #pragma unroll
    for (int ks = 0; ks < KD / 32; ks++) {
        f16x8 a0 = *(const f16x8*)(&As[arow * ROWB + ((ks * 64 + kg * 16) ^ ((arow & 7) << 4))]);
        f16x8 a1 = *(const f16x8*)(&As[(16 + arow) * ROWB + ((ks * 64 + kg * 16) ^ ((arow & 7) << 4))]);
        #pragma unroll
        for (int c = 0; c < NFRAG; c++) {
            f16x8 b = *(const f16x8*)(Bp +
                (((size_t)(wv * NFRAG + c) * (KD / 32) + ks) * 64 + lane) * 8);
            acc[c][0] = MFMA16(a0, b, acc[c][0]);
            acc[c][1] = MFMA16(a1, b, acc[c][1]);
        }
    }

    #pragma unroll
    for (int c = 0; c < NFRAG; c++) {
        int cg = (wv * NFRAG + c) * 16 + arow;
        float bb = bias ? bias[blockIdx.y * bias_ys + cg] : 0.f;
        #pragma unroll
        for (int rt = 0; rt < 2; rt++)
            #pragma unroll
            for (int rg = 0; rg < 4; rg++) {
                int grow = r0 + rt * 16 + kg * 4 + rg;
                float v = acc[c][rt][rg] + bb;
                if (RELU) v = fmaxf(v, 0.f);
                if (rowmask && rowmask[grow]) v = 0.f;
                if (C)   C[(size_t)grow * ldc + coff + cg] = (_Float16)v;
                if (C32) C32[(size_t)grow * ldc + coff + cg] = v;
            }
    }
}

// k2d: attention core. 1 query/wave, head per half-wave, no LDS/barriers,
// depth-1 pipelined gathers.
__global__ __launch_bounds__(256)
void k2d(const int* __restrict__ neighbors, const int* __restrict__ nb_eidx,
         const int* __restrict__ nb_et, const int* __restrict__ edge_times,
         const int* __restrict__ inv, const float* __restrict__ new_mem,
         const float* __restrict__ memory, const float* __restrict__ node_feats,
         const float* __restrict__ edge_feats, const float* __restrict__ time_w,
         const float* __restrict__ time_b, const float* __restrict__ bk,
         const _Float16* __restrict__ qbuf, _Float16* __restrict__ qk_wsum,
         int* __restrict__ allm)
{
    int tid = threadIdx.x;
    int qi = blockIdx.x * 4 + (tid >> 6);
    int lane = tid & 63;
    int h = lane >> 5, l32 = lane & 31;
    int c0 = l32 * 4;

    float4 tw = *(const float4*)(time_w + c0);
    float4 tb = *(const float4*)(time_b + c0);

    const _Float16* qkp = qk_wsum + (size_t)qi * 768 + h * 384;
    f16x4 t0 = *(const f16x4*)(qkp + c0);
    f16x4 t1 = *(const f16x4*)(qkp + 128 + c0);
    f16x4 t2 = *(const f16x4*)(qkp + 256 + c0);
    float qk0[4], qk1[4], qk2[4];
    #pragma unroll
    for (int t = 0; t < 4; t++) { qk0[t] = (float)t0[t]; qk1[t] = (float)t1[t]; qk2[t] = (float)t2[t]; }

    f16x4 qv = *(const f16x4*)(qbuf + (size_t)qi * 256 + h * 128 + c0);
    float4 bkv = *(const float4*)(bk + h * 128 + c0);
    float cb = (float)qv[0] * bkv.x + (float)qv[1] * bkv.y +
               (float)qv[2] * bkv.z + (float)qv[3] * bkv.w;
    cb += __shfl_xor(cb, 1, 32);
    cb += __shfl_xor(cb, 2, 32);
    cb += __shfl_xor(cb, 4, 32);
    cb += __shfl_xor(cb, 8, 32);
    cb += __shfl_xor(cb, 16, 32);

    float ts = (float)edge_times[qi & (BB - 1)];
    float m_run = -3.0e38f, l_run = 0.f;
    float w0[4] = {0,0,0,0}, w1[4] = {0,0,0,0}, w2[4] = {0,0,0,0};
    int anyv = 0;
    const float inv_sqrt = 0.08838834764831845f;

    int base = qi * KK;
    int nb_c = neighbors[base];
    int ei_c = nb_eidx[base];
    int et_c = nb_et[base];
    float4 mv, nf, ef;
    {
        int iv = inv[nb_c];
        const float* mp = (iv >= 0) ? (new_mem + (size_t)iv * 128) : (memory + (size_t)nb_c * 128);
        mv = *(const float4*)(mp + c0);
        nf = *(const float4*)(node_feats + (size_t)nb_c * 128 + c0);
        ef = *(const float4*)(edge_feats + (size_t)ei_c * 128 + c0);
    }

    for (int j = 0; j < KK; j++) {
        int nb_n = 0, ei_n = 0, et_n = 0;
        float4 mv_n = {0,0,0,0}, nf_n = {0,0,0,0}, ef_n = {0,0,0,0};
        if (j + 1 < KK) {
            nb_n = neighbors[base + j + 1];
            ei_n = nb_eidx[base + j + 1];
            et_n = nb_et[base + j + 1];
            int iv = inv[nb_n];
            const float* mp = (iv >= 0) ? (new_mem + (size_t)iv * 128) : (memory + (size_t)nb_n * 128);
            mv_n = *(const float4*)(mp + c0);
            nf_n = *(const float4*)(node_feats + (size_t)nb_n * 128 + c0);
            ef_n = *(const float4*)(edge_feats + (size_t)ei_n * 128 + c0);
        }

        float dtf = ts - (float)et_c;
        anyv |= (nb_c != 0);
        float k0[4] = { mv.x + nf.x, mv.y + nf.y, mv.z + nf.z, mv.w + nf.w };
        float k1[4] = { tenc(dtf, tw.x, tb.x), tenc(dtf, tw.y, tb.y),
                        tenc(dtf, tw.z, tb.z), tenc(dtf, tw.w, tb.w) };
        float k2[4] = { ef.x, ef.y, ef.z, ef.w };

        float sp = 0.f;
        #pragma unroll
        for (int t = 0; t < 4; t++)
            sp += qk0[t] * k0[t] + qk1[t] * k1[t] + qk2[t] * k2[t];
        sp += __shfl_xor(sp, 1, 32);
        sp += __shfl_xor(sp, 2, 32);
        sp += __shfl_xor(sp, 4, 32);
        sp += __shfl_xor(sp, 8, 32);
        sp += __shfl_xor(sp, 16, 32);

        float s = (sp + cb) * inv_sqrt;
        if (nb_c == 0) s = -1e9f;
        float m_new = fmaxf(m_run, s);
        float sc = __expf(m_run - m_new);
        float p = __expf(s - m_new);
        l_run = l_run * sc + p;
        #pragma unroll
        for (int t = 0; t < 4; t++) {
            w0[t] = w0[t] * sc + p * k0[t];
            w1[t] = w1[t] * sc + p * k1[t];
            w2[t] = w2[t] * sc + p * k2[t];
        }
        m_run = m_new;

        nb_c = nb_n; ei_c = ei_n; et_c = et_n;
        mv = mv_n; nf = nf_n; ef = ef_n;
    }

    float linv = __builtin_amdgcn_rcpf(l_run);
    _Float16* wp = qk_wsum + (size_t)qi * 768 + h * 384;
    f16x4 o0, o1, o2;
    #pragma unroll
    for (int t = 0; t < 4; t++) {
        o0[t] = (_Float16)(w0[t] * linv);
        o1[t] = (_Float16)(w1[t] * linv);
        o2[t] = (_Float16)(w2[t] * linv);
    }
    *(f16x4*)(wp + c0) = o0;
    *(f16x4*)(wp + 128 + c0) = o1;
    *(f16x4*)(wp + 256 + c0) = o2;
    if (lane == 0) allm[qi] = anyv ? 0 : 1;
}

extern "C" void kernel_launch(void* const* d_in, const int* in_sizes, int n_in,
                              void* d_out, int out_size, void* d_ws, size_t ws_size,
                              hipStream_t stream) {
    (void)in_sizes; (void)n_in; (void)out_size; (void)ws_size;
    const int* src_nodes  = (const int*)d_in[0];
    const int* dst_nodes  = (const int*)d_in[1];
    const int* neg_nodes  = (const int*)d_in[2];
    const int* edge_times = (const int*)d_in[3];
    const int* neighbors  = (const int*)d_in[4];
    const int* nb_eidx    = (const int*)d_in[5];
    const int* nb_et      = (const int*)d_in[6];
    const int* msg_src    = (const int*)d_in[7];
    const int* msg_dst    = (const int*)d_in[8];
    const int* msg_eidx   = (const int*)d_in[9];
    const int* msg_t      = (const int*)d_in[10];
    const int* last_update= (const int*)d_in[11];
    const float* node_feats = (const float*)d_in[12];
    const float* edge_feats = (const float*)d_in[13];
    const float* memory     = (const float*)d_in[14];
    const float* time_w = (const float*)d_in[15];
    const float* time_b = (const float*)d_in[16];
    const float* W1 = (const float*)d_in[17];
    const float* b1 = (const float*)d_in[18];
    const float* W2 = (const float*)d_in[19];
    const float* b2 = (const float*)d_in[20];
    const float* gWi = (const float*)d_in[21];
    const float* gWh = (const float*)d_in[22];
    const float* gbi = (const float*)d_in[23];
    const float* gbh = (const float*)d_in[24];
    const float* Wq = (const float*)d_in[25];
    const float* bq = (const float*)d_in[26];
    const float* Wk = (const float*)d_in[27];
    const float* bk = (const float*)d_in[28];
    const float* Wv = (const float*)d_in[29];
    const float* bv = (const float*)d_in[30];
    const float* Wo = (const float*)d_in[31];
    const float* bo = (const float*)d_in[32];
    const float* mW1 = (const float*)d_in[33];
    const float* mb1 = (const float*)d_in[34];
    const float* mW2 = (const float*)d_in[35];
    const float* mb2 = (const float*)d_in[36];
    float* out = (float*)d_out;

    char* w = (char*)d_ws;
    int* lastpos = (int*)w;
    int* inv  = lastpos + NN;
    int* comp = inv + NN;
    int* count = comp + NN;
    size_t off = ((size_t)(3 * NN + 1) * 4 + 255) & ~(size_t)255;
    float* new_mem = (float*)(w + off);               // MM*128 f32
    size_t woff = off + (size_t)MM * 128 * 4;

    _Float16* Hpool = (_Float16*)(w + woff);          // 655360 f16, fragment order
    _Float16* W1h  = Hpool;
    _Float16* W2h  = Hpool + 131072;
    _Float16* Wih  = Hpool + 163840;
    _Float16* Whh  = Hpool + 212992;
    _Float16* Wqh  = Hpool + 262144;
    _Float16* Wvh  = Hpool + 327680;
    _Float16* Woh  = Hpool + 425984;
    _Float16* mW1h = Hpool + 491520;
    _Float16* mW2h = Hpool + 540672;
    _Float16* Wkth = Hpool + 557056;
    size_t boff = woff + (size_t)655360 * 2;

    _Float16* qin_ctx = (_Float16*)(w + boff);
    _Float16* q_hm    = qin_ctx + (size_t)Q3 * 256;
    _Float16* qk_ws   = q_hm + (size_t)Q3 * 256;
    _Float16* acat    = qk_ws + (size_t)Q3 * 768;
    int* allm         = (int*)(acat + (size_t)Q3 * 384);

    k_init<<<dim3((NN + 255) / 256), dim3(256), 0, stream>>>(lastpos, inv, count);
    k_scatter<<<dim3((MM + 255) / 256), dim3(256), 0, stream>>>(msg_src, lastpos);
    k_compact<<<dim3((NN + 255) / 256), dim3(256), 0, stream>>>(lastpos, inv, comp, count);
    k_cvtw<<<dim3(320), dim3(256), 0, stream>>>(W1, W2, gWi, gWh, Wq, Wv, Wo, mW1, mW2, Wk, Hpool);
    k_stage1<<<dim3((MM + 31) / 32), dim3(512), 0, stream>>>(
        comp, count, lastpos, msg_dst, msg_eidx, msg_t, last_update,
        memory, edge_feats, time_w, time_b,
        W1h, b1, W2h, b2, Wih, Whh, gbi, gbh, new_mem);

    k2a<<<dim3(Q3 / 32), dim3(256), 0, stream>>>(
        src_nodes, dst_nodes, neg_nodes, inv, new_mem, memory, node_feats, time_b,
        qin_ctx, acat);
    k_gemm<256, 4, false><<<dim3(Q3 / 32, 1), dim3(256), 0, stream>>>(
        qin_ctx, 256, 0, Wqh, 0, bq, 0, q_hm, 256, 0, nullptr, nullptr);
    k_gemm<128, 6, false><<<dim3(Q3 / 32, 2), dim3(256), 0, stream>>>(
        q_hm, 256, 128, Wkth, 384 * 128, nullptr, 0, qk_ws, 768, 384, nullptr, nullptr);
    k2d<<<dim3(Q3 / 4), dim3(256), 0, stream>>>(
        neighbors, nb_eidx, nb_et, edge_times, inv, new_mem, memory, node_feats,
        edge_feats, time_w, time_b, bk, q_hm, qk_ws, allm);
    k_gemm<384, 2, false><<<dim3(Q3 / 32, 2), dim3(256), 0, stream>>>(
        qk_ws, 768, 384, Wvh, 128 * 384, bv, 128, qin_ctx, 256, 128, nullptr, nullptr);
    k_gemm<256, 4, false><<<dim3(Q3 / 32, 1), dim3(256), 0, stream>>>(
        qin_ctx, 256, 0, Woh, 0, bo, 0, acat, 384, 0, nullptr, allm);
    k_gemm<384, 2, true><<<dim3(Q3 / 32, 1), dim3(256), 0, stream>>>(
        acat, 384, 0, mW1h, 0, mb1, 0, q_hm, 128, 0, nullptr, nullptr);
    k_gemm<128, 2, false><<<dim3(Q3 / 32, 1), dim3(256), 0, stream>>>(
        q_hm, 128, 0, mW2h, 0, mb2, 0, nullptr, 128, 0, out, nullptr);
}

// Round 6
// 358.116 us; speedup vs baseline: 6.4999x; 1.0868x over previous
//
#include <hip/hip_runtime.h>
#include <math.h>

#define NN 200000
#define EEDGE 500000
#define BB 4096
#define KK 20
#define MM 100000
#define Q3 (3*BB)

typedef _Float16 __attribute__((ext_vector_type(8))) f16x8;
typedef _Float16 __attribute__((ext_vector_type(4))) f16x4;
typedef float __attribute__((ext_vector_type(4))) f32x4;

#define MFMA16(a,b,c) __builtin_amdgcn_mfma_f32_16x16x32_f16(a,b,c,0,0,0)

// cos(a) for |a| up to ~1e7: f64 range-reduction to revolutions + v_cos_f32.
__device__ __forceinline__ float fast_cos(float a) {
    double ad = (double)a * 0.15915494309189535;   // 1/(2*pi)
    double fr = ad - floor(ad);                    // [0,1) revolutions
    return __builtin_amdgcn_cosf((float)fr);       // cos(2*pi*x)
}

// time encoding matching numpy's f32 arg rounding — NO fma contraction.
__device__ __forceinline__ float tenc(float dt, float w, float b) {
    float p = __fmul_rn(dt, w);
    float a = __fadd_rn(p, b);
    return fast_cos(a);
}

__device__ __forceinline__ float fsigm(float x) {
    return __builtin_amdgcn_rcpf(1.f + __expf(-x));
}
__device__ __forceinline__ float ftanh(float x) {
    return 1.f - 2.f * __builtin_amdgcn_rcpf(1.f + __expf(2.f * x));
}

__device__ __forceinline__ f32x4 z4() {
    f32x4 v; v[0] = 0.f; v[1] = 0.f; v[2] = 0.f; v[3] = 0.f; return v;
}

__global__ void k_scatter(const int* __restrict__ msg_src, int* __restrict__ lastpos) {
    int i = blockIdx.x * 256 + threadIdx.x;
    if (i < MM) atomicMax(&lastpos[msg_src[i]], i);
}

__global__ void k_compact(const int* __restrict__ lastpos, int* __restrict__ inv,
                          int* __restrict__ comp, int* __restrict__ count) {
    int n = blockIdx.x * 256 + threadIdx.x;
    if (n < NN && lastpos[n] >= 0) {
        int j = atomicAdd(count, 1);
        comp[j] = n;
        inv[n] = j;
    }
}

// f32 -> f16 weight conversion into MFMA FRAGMENT ORDER:
// elem offset = matbase + ((cgrp*KS + ks)*64 + lane)*8 + e
__global__ void k_cvtw(const float* __restrict__ W1, const float* __restrict__ W2,
                       const float* __restrict__ Wi, const float* __restrict__ Wh,
                       const float* __restrict__ Wq, const float* __restrict__ Wv,
                       const float* __restrict__ Wo, const float* __restrict__ mW1,
                       const float* __restrict__ mW2, const float* __restrict__ Wk,
                       _Float16* __restrict__ dst) {
    int f = blockIdx.x * 256 + threadIdx.x;   // fragment id, 81920 total
    if (f >= 81920) return;
    const float* src; int dstoff, K, lf, tr = -1;
    if      (f < 16384) { src = W1;  dstoff = 0;      K = 512; lf = f; }
    else if (f < 20480) { src = W2;  dstoff = 131072; K = 256; lf = f - 16384; }
    else if (f < 26624) { src = Wi;  dstoff = 163840; K = 128; lf = f - 20480; }
    else if (f < 32768) { src = Wh;  dstoff = 212992; K = 128; lf = f - 26624; }
    else if (f < 40960) { src = Wq;  dstoff = 262144; K = 256; lf = f - 32768; }
    else if (f < 47104) { src = Wv;  dstoff = 327680; K = 384; lf = f - 40960; }
    else if (f < 53248) { src = Wv + 128 * 384; dstoff = 376832; K = 384; lf = f - 47104; }
    else if (f < 61440) { src = Wo;  dstoff = 425984; K = 256; lf = f - 53248; }
    else if (f < 67584) { src = mW1; dstoff = 491520; K = 384; lf = f - 61440; }
    else if (f < 69632) { src = mW2; dstoff = 540672; K = 128; lf = f - 67584; }
    else if (f < 75776) { src = Wk;  dstoff = 557056; K = 128; lf = f - 69632; tr = 0; }
    else                { src = Wk;  dstoff = 606208; K = 128; lf = f - 75776; tr = 1; }
    int KS = K >> 5;
    int cgrp = lf / (KS * 64);
    int rem  = lf - cgrp * (KS * 64);
    int ks = rem >> 6, lane = rem & 63;
    int kg = lane >> 4, arow = lane & 15;
    int col = cgrp * 16 + arow;
    int k0 = ks * 32 + kg * 8;
    f16x8 h;
    if (tr < 0) {
        const float* p = src + (size_t)col * K + k0;
        float4 a = *(const float4*)p;
        float4 b = *(const float4*)(p + 4);
        h[0] = (_Float16)a.x; h[1] = (_Float16)a.y; h[2] = (_Float16)a.z; h[3] = (_Float16)a.w;
        h[4] = (_Float16)b.x; h[5] = (_Float16)b.y; h[6] = (_Float16)b.z; h[7] = (_Float16)b.w;
    } else {
        #pragma unroll
        for (int e = 0; e < 8; e++)
            h[e] = (_Float16)Wk[(size_t)(tr * 128 + k0 + e) * 384 + col];
    }
    *(f16x8*)(dst + dstoff + (size_t)lf * 8) = h;
}

// ---------------- Stage 1: 64 rows/block, 512 threads / 8 waves ----------------
__device__ __forceinline__ int SWA(int r, int byteofs) {
    return r * 1024 + (byteofs ^ ((r & 7) << 4));
}

// fragment-order weight load, K=128 (KS=4)
__device__ __forceinline__ f16x8 ldw4(const _Float16* W, int cg, int ks, int lane) {
    return *(const f16x8*)(W + (((size_t)cg * 4 + ks) * 64 + lane) * 8);
}

__global__ __launch_bounds__(512, 4)
void k_stage1(const int* __restrict__ comp, const int* __restrict__ count,
              const int* __restrict__ lastpos,
              const int* __restrict__ msg_dst, const int* __restrict__ msg_eidx,
              const int* __restrict__ msg_t, const int* __restrict__ last_update,
              const float* __restrict__ memory, const float* __restrict__ edge_feats,
              const float* __restrict__ time_w, const float* __restrict__ time_b,
              const _Float16* __restrict__ W1h, const float* __restrict__ b1,
              const _Float16* __restrict__ W2h, const float* __restrict__ b2,
              const _Float16* __restrict__ Wih, const _Float16* __restrict__ Whh,
              const float* __restrict__ bi, const float* __restrict__ bh,
              _Float16* __restrict__ new_mem)
{
    __shared__ char rawb[64 * 1024];
    __shared__ int sn[64], sd[64], se[64];
    __shared__ float sdt[64];

    int cnt = *count;
    int r0 = blockIdx.x * 64;
    if (r0 >= cnt) return;
    int tid = threadIdx.x;

    if (tid < 64) {
        int rr = r0 + tid;
        int j = (rr < cnt) ? rr : r0;
        int n = comp[j];
        int idx = lastpos[n];
        sn[tid] = n;
        sd[tid] = msg_dst[idx];
        se[tid] = msg_eidx[idx];
        sdt[tid] = (float)(msg_t[idx] - last_update[n]);
    }
    __syncthreads();

    // data pass: 64 rows x 48 granules (mem[n] | mem[d] | edge)
    #pragma unroll
    for (int it = 0; it < 6; it++) {
        int gi = tid + it * 512;
        int r = gi / 48, g = gi - r * 48;
        const float* src;
        if (g < 16)      src = memory + (size_t)sn[r] * 128 + g * 8;
        else if (g < 32) src = memory + (size_t)sd[r] * 128 + (g - 16) * 8;
        else             src = edge_feats + (size_t)se[r] * 128 + (g - 32) * 8;
        float4 a = *(const float4*)src;
        float4 b = *(const float4*)(src + 4);
        f16x8 h;
        h[0] = (_Float16)a.x; h[1] = (_Float16)a.y; h[2] = (_Float16)a.z; h[3] = (_Float16)a.w;
        h[4] = (_Float16)b.x; h[5] = (_Float16)b.y; h[6] = (_Float16)b.z; h[7] = (_Float16)b.w;
        *(f16x8*)(rawb + SWA(r, g * 16)) = h;
    }
    // tenc pass: 64 rows x 16 granules
    #pragma unroll
    for (int it = 0; it < 2; it++) {
        int gi = tid + it * 512;
        int r = gi >> 4, g = gi & 15;
        int c = g * 8;
        float dt = sdt[r];
        float4 w0 = *(const float4*)(time_w + c);
        float4 w1 = *(const float4*)(time_w + c + 4);
        float4 t0 = *(const float4*)(time_b + c);
        float4 t1 = *(const float4*)(time_b + c + 4);
        f16x8 h;
        h[0] = (_Float16)tenc(dt, w0.x, t0.x); h[1] = (_Float16)tenc(dt, w0.y, t0.y);
        h[2] = (_Float16)tenc(dt, w0.z, t0.z); h[3] = (_Float16)tenc(dt, w0.w, t0.w);
        h[4] = (_Float16)tenc(dt, w1.x, t1.x); h[5] = (_Float16)tenc(dt, w1.y, t1.y);
        h[6] = (_Float16)tenc(dt, w1.z, t1.z); h[7] = (_Float16)tenc(dt, w1.w, t1.w);
        *(f16x8*)(rawb + SWA(r, (48 + g) * 16)) = h;
    }
    __syncthreads();

    int wv = tid >> 6, lane = tid & 63;
    int arow = lane & 15, kg = lane >> 4;

    // GEMM1: h1[64][256], K=512; wave owns 2 col-groups; B reused over 4 row-tiles
    f32x4 acc1[2][4];
    #pragma unroll
    for (int c = 0; c < 2; c++)
        #pragma unroll
        for (int rt = 0; rt < 4; rt++) acc1[c][rt] = z4();
    for (int ks = 0; ks < 16; ks++) {
        f16x8 a[4];
        #pragma unroll
        for (int rt = 0; rt < 4; rt++)
            a[rt] = *(const f16x8*)(rawb + SWA(rt * 16 + arow, ks * 64 + kg * 16));
        #pragma unroll
        for (int c = 0; c < 2; c++) {
            f16x8 b = *(const f16x8*)(W1h + (((size_t)(wv * 2 + c) * 16 + ks) * 64 + lane) * 8);
            #pragma unroll
            for (int rt = 0; rt < 4; rt++)
                acc1[c][rt] = MFMA16(a[rt], b, acc1[c][rt]);
        }
    }
    __syncthreads();

    #pragma unroll
    for (int c = 0; c < 2; c++) {
        int col = (wv * 2 + c) * 16 + arow;
        float bb = b1[col];
        #pragma unroll
        for (int rt = 0; rt < 4; rt++)
            #pragma unroll
            for (int rg = 0; rg < 4; rg++) {
                int row = rt * 16 + kg * 4 + rg;
                float v = fmaxf(acc1[c][rt][rg] + bb, 0.f);
                *(_Float16*)(rawb + SWA(row, 384 + col * 2)) = (_Float16)v;
            }
    }
    __syncthreads();

    // GEMM2: msg[64][128], K=256; wave owns 1 col-group
    f32x4 acc2[4];
    #pragma unroll
    for (int rt = 0; rt < 4; rt++) acc2[rt] = z4();
    for (int ks = 0; ks < 8; ks++) {
        f16x8 b = *(const f16x8*)(W2h + (((size_t)wv * 8 + ks) * 64 + lane) * 8);
        #pragma unroll
        for (int rt = 0; rt < 4; rt++) {
            f16x8 a = *(const f16x8*)(rawb + SWA(rt * 16 + arow, 384 + ks * 64 + kg * 16));
            acc2[rt] = MFMA16(a, b, acc2[rt]);
        }
    }
    __syncthreads();

    {
        int col = wv * 16 + arow;
        float bb = b2[col];
        #pragma unroll
        for (int rt = 0; rt < 4; rt++)
            #pragma unroll
            for (int rg = 0; rg < 4; rg++) {
                int row = rt * 16 + kg * 4 + rg;
                *(_Float16*)(rawb + SWA(row, 384 + col * 2)) =
                    (_Float16)(acc2[rt][rg] + bb);
            }
    }
    __syncthreads();

    // GRU gates, one gate-pass at a time (keeps live acc small)
    f32x4 aR[4], aZ[4], aNi[4], aNh[4];
    #pragma unroll
    for (int rt = 0; rt < 4; rt++) { aR[rt] = z4(); aZ[rt] = z4(); aNi[rt] = z4(); aNh[rt] = z4(); }
    for (int ks = 0; ks < 4; ks++) {   // r gate
        f16x8 bi_ = ldw4(Wih, wv, ks, lane);
        f16x8 bh_ = ldw4(Whh, wv, ks, lane);
        #pragma unroll
        for (int rt = 0; rt < 4; rt++) {
            f16x8 m = *(const f16x8*)(rawb + SWA(rt * 16 + arow, 384 + ks * 64 + kg * 16));
            f16x8 hh = *(const f16x8*)(rawb + SWA(rt * 16 + arow, ks * 64 + kg * 16));
            aR[rt] = MFMA16(m, bi_, aR[rt]);
            aR[rt] = MFMA16(hh, bh_, aR[rt]);
        }
    }
    for (int ks = 0; ks < 4; ks++) {   // z gate
        f16x8 bi_ = ldw4(Wih, 8 + wv, ks, lane);
        f16x8 bh_ = ldw4(Whh, 8 + wv, ks, lane);
        #pragma unroll
        for (int rt = 0; rt < 4; rt++) {
            f16x8 m = *(const f16x8*)(rawb + SWA(rt * 16 + arow, 384 + ks * 64 + kg * 16));
            f16x8 hh = *(const f16x8*)(rawb + SWA(rt * 16 + arow, ks * 64 + kg * 16));
            aZ[rt] = MFMA16(m, bi_, aZ[rt]);
            aZ[rt] = MFMA16(hh, bh_, aZ[rt]);
        }
    }
    for (int ks = 0; ks < 4; ks++) {   // n gates
        f16x8 bi_ = ldw4(Wih, 16 + wv, ks, lane);
        f16x8 bh_ = ldw4(Whh, 16 + wv, ks, lane);
        #pragma unroll
        for (int rt = 0; rt < 4; rt++) {
            f16x8 m = *(const f16x8*)(rawb + SWA(rt * 16 + arow, 384 + ks * 64 + kg * 16));
            f16x8 hh = *(const f16x8*)(rawb + SWA(rt * 16 + arow, ks * 64 + kg * 16));
            aNi[rt] = MFMA16(m, bi_, aNi[rt]);
            aNh[rt] = MFMA16(hh, bh_, aNh[rt]);
        }
    }

    {
        int col = wv * 16 + arow;
        float bir = bi[col],        bhr = bh[col];
        float biz = bi[128 + col],  bhz = bh[128 + col];
        float bin_ = bi[256 + col], bhn_ = bh[256 + col];
        #pragma unroll
        for (int rt = 0; rt < 4; rt++)
            #pragma unroll
            for (int rg = 0; rg < 4; rg++) {
                int row = rt * 16 + kg * 4 + rg;
                int rr = r0 + row;
                if (rr < cnt) {
                    float r_ = fsigm(aR[rt][rg] + bir + bhr);
                    float zg = fsigm(aZ[rt][rg] + biz + bhz);
                    float ng = ftanh(aNi[rt][rg] + bin_ + r_ * (aNh[rt][rg] + bhn_));
                    float om = (float)*(const _Float16*)(rawb + SWA(row, col * 2));
                    new_mem[(size_t)rr * 128 + col] = (_Float16)((1.f - zg) * ng + zg * om);
                }
            }
    }
}

// k_feat: feat[n] = (updated ? new_mem[inv[n]] : memory[n]) + node_feats[n], f16
__global__ __launch_bounds__(256)
void k_feat(const int* __restrict__ inv, const _Float16* __restrict__ new_mem,
            const float* __restrict__ memory, const float* __restrict__ node_feats,
            _Float16* __restrict__ feat)
{
    int idx = blockIdx.x * 256 + threadIdx.x;
    if (idx >= NN * 16) return;
    int n = idx >> 4, g = idx & 15;
    int c = g * 8;
    int iv = inv[n];
    float4 n0 = *(const float4*)(node_feats + (size_t)n * 128 + c);
    float4 n1 = *(const float4*)(node_feats + (size_t)n * 128 + c + 4);
    f16x8 o;
    if (iv >= 0) {
        f16x8 mv = *(const f16x8*)(new_mem + (size_t)iv * 128 + c);
        o[0] = (_Float16)((float)mv[0] + n0.x); o[1] = (_Float16)((float)mv[1] + n0.y);
        o[2] = (_Float16)((float)mv[2] + n0.z); o[3] = (_Float16)((float)mv[3] + n0.w);
        o[4] = (_Float16)((float)mv[4] + n1.x); o[5] = (_Float16)((float)mv[5] + n1.y);
        o[6] = (_Float16)((float)mv[6] + n1.z); o[7] = (_Float16)((float)mv[7] + n1.w);
    } else {
        float4 m0 = *(const float4*)(memory + (size_t)n * 128 + c);
        float4 m1 = *(const float4*)(memory + (size_t)n * 128 + c + 4);
        o[0] = (_Float16)(m0.x + n0.x); o[1] = (_Float16)(m0.y + n0.y);
        o[2] = (_Float16)(m0.z + n0.z); o[3] = (_Float16)(m0.w + n0.w);
        o[4] = (_Float16)(m1.x + n1.x); o[5] = (_Float16)(m1.y + n1.y);
        o[6] = (_Float16)(m1.z + n1.z); o[7] = (_Float16)(m1.w + n1.w);
    }
    *(f16x8*)(feat + (size_t)n * 128 + c) = o;
}

// ---------------- Stage 2 ----------------
__global__ void k2a(const int* __restrict__ src_nodes, const int* __restrict__ dst_nodes,
                    const int* __restrict__ neg_nodes, const _Float16* __restrict__ feat,
                    const float* __restrict__ time_b,
                    _Float16* __restrict__ q_in, _Float16* __restrict__ acat)
{
    __shared__ int snode[32];
    int tid = threadIdx.x;
    int r0 = blockIdx.x * 32;
    if (tid < 32) {
        int q = r0 + tid;
        snode[tid] = (q < BB) ? src_nodes[q] : (q < 2 * BB) ? dst_nodes[q - BB] : neg_nodes[q - 2 * BB];
    }
    __syncthreads();
    #pragma unroll
    for (int it = 0; it < 4; it++) {
        int gi = tid + it * 256;
        int r = gi >> 5, ch = gi & 31;
        int c = ch * 4;
        int node = snode[r];
        f16x4 sf = *(const f16x4*)(feat + (size_t)node * 128 + c);
        size_t q = (size_t)(r0 + r);
        *(f16x4*)(q_in + q * 256 + c) = sf;
        *(f16x4*)(acat + q * 384 + 256 + c) = sf;
        float4 tb = *(const float4*)(time_b + c);
        f16x4 te;
        te[0] = (_Float16)fast_cos(tb.x); te[1] = (_Float16)fast_cos(tb.y);
        te[2] = (_Float16)fast_cos(tb.z); te[3] = (_Float16)fast_cos(tb.w);
        *(f16x4*)(q_in + q * 256 + 128 + c) = te;
    }
}

// generic 32-row-tile MFMA GEMM, fragment-ordered B.
template<int KD, int NFRAG, bool RELU>
__global__ __launch_bounds__(256, 4)
void k_gemm(const _Float16* __restrict__ A, int lda, int a_ys,
            const _Float16* __restrict__ B, int b_ys,
            const float* __restrict__ bias, int bias_ys,
            _Float16* __restrict__ C, int ldc, int c_ys,
            float* __restrict__ C32,
            const int* __restrict__ rowmask)
{
    constexpr int ROWB = KD * 2;
    __shared__ char As[32 * ROWB];
    int tid = threadIdx.x;
    int r0 = blockIdx.x * 32;
    int aoff = blockIdx.y * a_ys;
    const _Float16* Bp = B + (size_t)blockIdx.y * b_ys;
    int coff = blockIdx.y * c_ys;

    #pragma unroll
    for (int t = 0; t < (32 * KD / 8) / 256; t++) {
        int gi = tid + t * 256;
        int r = gi / (KD / 8), g = gi % (KD / 8);
        f16x8 v = *(const f16x8*)(A + (size_t)(r0 + r) * lda + aoff + g * 8);
        *(f16x8*)(&As[r * ROWB + ((g * 16) ^ ((r & 7) << 4))]) = v;
    }
    __syncthreads();

    int wv = tid >> 6, lane = tid & 63;
    int arow = lane & 15, kg = lane >> 4;
    f32x4 acc[NFRAG][2];
    #pragma unroll
    for (int c = 0; c < NFRAG; c++) { acc[c][0] = z4(); acc[c][1] = z4(); }

    #pragma unroll
    for (int ks = 0; ks < KD / 32; ks++) {
        f16x8 a0 = *(const f16x8*)(&As[arow * ROWB + ((ks * 64 + kg * 16) ^ ((arow & 7) << 4))]);
        f16x8 a1 = *(const f16x8*)(&As[(16 + arow) * ROWB + ((ks * 64 + kg * 16) ^ ((arow & 7) << 4))]);
        #pragma unroll
        for (int c = 0; c < NFRAG; c++) {
            f16x8 b = *(const f16x8*)(Bp +
                (((size_t)(wv * NFRAG + c) * (KD / 32) + ks) * 64 + lane) * 8);
            acc[c][0] = MFMA16(a0, b, acc[c][0]);
            acc[c][1] = MFMA16(a1, b, acc[c][1]);
        }
    }

    #pragma unroll
    for (int c = 0; c < NFRAG; c++) {
        int cg = (wv * NFRAG + c) * 16 + arow;
        float bb = bias ? bias[blockIdx.y * bias_ys + cg] : 0.f;
        #pragma unroll
        for (int rt = 0; rt < 2; rt++)
            #pragma unroll
            for (int rg = 0; rg < 4; rg++) {
                int grow = r0 + rt * 16 + kg * 4 + rg;
                float v = acc[c][rt][rg] + bb;
                if (RELU) v = fmaxf(v, 0.f);
                if (rowmask && rowmask[grow]) v = 0.f;
                if (C)   C[(size_t)grow * ldc + coff + cg] = (_Float16)v;
                if (C32) C32[(size_t)grow * ldc + coff + cg] = v;
            }
    }
}

// k2d: attention core. 1 query/wave, head per half-wave, no LDS/barriers,
// depth-1 pipelined gathers; feat (f16) replaces mem+node_feats+inv.
__global__ __launch_bounds__(256)
void k2d(const int* __restrict__ neighbors, const int* __restrict__ nb_eidx,
         const int* __restrict__ nb_et, const int* __restrict__ edge_times,
         const _Float16* __restrict__ feat,
         const float* __restrict__ edge_feats, const float* __restrict__ time_w,
         const float* __restrict__ time_b, const float* __restrict__ bk,
         const _Float16* __restrict__ qbuf, _Float16* __restrict__ qk_wsum,
         int* __restrict__ allm)
{
    int tid = threadIdx.x;
    int qi = blockIdx.x * 4 + (tid >> 6);
    int lane = tid & 63;
    int h = lane >> 5, l32 = lane & 31;
    int c0 = l32 * 4;

    float4 tw = *(const float4*)(time_w + c0);
    float4 tb = *(const float4*)(time_b + c0);

    const _Float16* qkp = qk_wsum + (size_t)qi * 768 + h * 384;
    f16x4 t0 = *(const f16x4*)(qkp + c0);
    f16x4 t1 = *(const f16x4*)(qkp + 128 + c0);
    f16x4 t2 = *(const f16x4*)(qkp + 256 + c0);
    float qk0[4], qk1[4], qk2[4];
    #pragma unroll
    for (int t = 0; t < 4; t++) { qk0[t] = (float)t0[t]; qk1[t] = (float)t1[t]; qk2[t] = (float)t2[t]; }

    f16x4 qv = *(const f16x4*)(qbuf + (size_t)qi * 256 + h * 128 + c0);
    float4 bkv = *(const float4*)(bk + h * 128 + c0);
    float cb = (float)qv[0] * bkv.x + (float)qv[1] * bkv.y +
               (float)qv[2] * bkv.z + (float)qv[3] * bkv.w;
    cb += __shfl_xor(cb, 1, 32);
    cb += __shfl_xor(cb, 2, 32);
    cb += __shfl_xor(cb, 4, 32);
    cb += __shfl_xor(cb, 8, 32);
    cb += __shfl_xor(cb, 16, 32);

    float ts = (float)edge_times[qi & (BB - 1)];
    float m_run = -3.0e38f, l_run = 0.f;
    float w0[4] = {0,0,0,0}, w1[4] = {0,0,0,0}, w2[4] = {0,0,0,0};
    int anyv = 0;
    const float inv_sqrt = 0.08838834764831845f;

    int base = qi * KK;
    int nb_c = neighbors[base];
    int ei_c = nb_eidx[base];
    int et_c = nb_et[base];
    f16x4 fv;
    float4 ef;
    {
        fv = *(const f16x4*)(feat + (size_t)nb_c * 128 + c0);
        ef = *(const float4*)(edge_feats + (size_t)ei_c * 128 + c0);
    }

    for (int j = 0; j < KK; j++) {
        int nb_n = 0, ei_n = 0, et_n = 0;
        f16x4 fv_n = {0,0,0,0};
        float4 ef_n = {0,0,0,0};
        if (j + 1 < KK) {
            nb_n = neighbors[base + j + 1];
            ei_n = nb_eidx[base + j + 1];
            et_n = nb_et[base + j + 1];
            fv_n = *(const f16x4*)(feat + (size_t)nb_n * 128 + c0);
            ef_n = *(const float4*)(edge_feats + (size_t)ei_n * 128 + c0);
        }

        float dtf = ts - (float)et_c;
        anyv |= (nb_c != 0);
        float k0[4] = { (float)fv[0], (float)fv[1], (float)fv[2], (float)fv[3] };
        float k1[4] = { tenc(dtf, tw.x, tb.x), tenc(dtf, tw.y, tb.y),
                        tenc(dtf, tw.z, tb.z), tenc(dtf, tw.w, tb.w) };
        float k2[4] = { ef.x, ef.y, ef.z, ef.w };

        float sp = 0.f;
        #pragma unroll
        for (int t = 0; t < 4; t++)
            sp += qk0[t] * k0[t] + qk1[t] * k1[t] + qk2[t] * k2[t];
        sp += __shfl_xor(sp, 1, 32);
        sp += __shfl_xor(sp, 2, 32);
        sp += __shfl_xor(sp, 4, 32);
        sp += __shfl_xor(sp, 8, 32);
        sp += __shfl_xor(sp, 16, 32);

        float s = (sp + cb) * inv_sqrt;
        if (nb_c == 0) s = -1e9f;
        float m_new = fmaxf(m_run, s);
        float sc = __expf(m_run - m_new);
        float p = __expf(s - m_new);
        l_run = l_run * sc + p;
        #pragma unroll
        for (int t = 0; t < 4; t++) {
            w0[t] = w0[t] * sc + p * k0[t];
            w1[t] = w1[t] * sc + p * k1[t];
            w2[t] = w2[t] * sc + p * k2[t];
        }
        m_run = m_new;

        nb_c = nb_n; ei_c = ei_n; et_c = et_n;
        fv = fv_n; ef = ef_n;
    }

    float linv = __builtin_amdgcn_rcpf(l_run);
    _Float16* wp = qk_wsum + (size_t)qi * 768 + h * 384;
    f16x4 o0, o1, o2;
    #pragma unroll
    for (int t = 0; t < 4; t++) {
        o0[t] = (_Float16)(w0[t] * linv);
        o1[t] = (_Float16)(w1[t] * linv);
        o2[t] = (_Float16)(w2[t] * linv);
    }
    *(f16x4*)(wp + c0) = o0;
    *(f16x4*)(wp + 128 + c0) = o1;
    *(f16x4*)(wp + 256 + c0) = o2;
    if (lane == 0) allm[qi] = anyv ? 0 : 1;
}

extern "C" void kernel_launch(void* const* d_in, const int* in_sizes, int n_in,
                              void* d_out, int out_size, void* d_ws, size_t ws_size,
                              hipStream_t stream) {
    (void)in_sizes; (void)n_in; (void)out_size; (void)ws_size;
    const int* src_nodes  = (const int*)d_in[0];
    const int* dst_nodes  = (const int*)d_in[1];
    const int* neg_nodes  = (const int*)d_in[2];
    const int* edge_times = (const int*)d_in[3];
    const int* neighbors  = (const int*)d_in[4];
    const int* nb_eidx    = (const int*)d_in[5];
    const int* nb_et      = (const int*)d_in[6];
    const int* msg_src    = (const int*)d_in[7];
    const int* msg_dst    = (const int*)d_in[8];
    const int* msg_eidx   = (const int*)d_in[9];
    const int* msg_t      = (const int*)d_in[10];
    const int* last_update= (const int*)d_in[11];
    const float* node_feats = (const float*)d_in[12];
    const float* edge_feats = (const float*)d_in[13];
    const float* memory     = (const float*)d_in[14];
    const float* time_w = (const float*)d_in[15];
    const float* time_b = (const float*)d_in[16];
    const float* W1 = (const float*)d_in[17];
    const float* b1 = (const float*)d_in[18];
    const float* W2 = (const float*)d_in[19];
    const float* b2 = (const float*)d_in[20];
    const float* gWi = (const float*)d_in[21];
    const float* gWh = (const float*)d_in[22];
    const float* gbi = (const float*)d_in[23];
    const float* gbh = (const float*)d_in[24];
    const float* Wq = (const float*)d_in[25];
    const float* bq = (const float*)d_in[26];
    const float* Wk = (const float*)d_in[27];
    const float* bk = (const float*)d_in[28];
    const float* Wv = (const float*)d_in[29];
    const float* bv = (const float*)d_in[30];
    const float* Wo = (const float*)d_in[31];
    const float* bo = (const float*)d_in[32];
    const float* mW1 = (const float*)d_in[33];
    const float* mb1 = (const float*)d_in[34];
    const float* mW2 = (const float*)d_in[35];
    const float* mb2 = (const float*)d_in[36];
    float* out = (float*)d_out;

    char* w = (char*)d_ws;
    int* lastpos = (int*)w;
    int* inv  = lastpos + NN;
    int* comp = inv + NN;
    int* count = comp + NN;
    size_t off = ((size_t)(3 * NN + 1) * 4 + 255) & ~(size_t)255;
    _Float16* new_mem = (_Float16*)(w + off);         // MM*128 f16 (25.6 MB)
    size_t foff = off + (size_t)MM * 128 * 2;
    _Float16* feat = (_Float16*)(w + foff);           // NN*128 f16 (51.2 MB)
    size_t woff = foff + (size_t)NN * 128 * 2;

    _Float16* Hpool = (_Float16*)(w + woff);          // 655360 f16, fragment order
    _Float16* W1h  = Hpool;
    _Float16* W2h  = Hpool + 131072;
    _Float16* Wih  = Hpool + 163840;
    _Float16* Whh  = Hpool + 212992;
    _Float16* Wqh  = Hpool + 262144;
    _Float16* Wvh  = Hpool + 327680;
    _Float16* Woh  = Hpool + 425984;
    _Float16* mW1h = Hpool + 491520;
    _Float16* mW2h = Hpool + 540672;
    _Float16* Wkth = Hpool + 557056;
    size_t boff = woff + (size_t)655360 * 2;

    _Float16* qin_ctx = (_Float16*)(w + boff);
    _Float16* q_hm    = qin_ctx + (size_t)Q3 * 256;
    _Float16* qk_ws   = q_hm + (size_t)Q3 * 256;
    _Float16* acat    = qk_ws + (size_t)Q3 * 768;
    int* allm         = (int*)(acat + (size_t)Q3 * 384);

    // lastpos = inv = -1 (0xFF bytes), count = 0
    hipMemsetAsync(lastpos, 0xFF, (size_t)2 * NN * 4, stream);
    hipMemsetAsync(count, 0, 4, stream);
    k_scatter<<<dim3((MM + 255) / 256), dim3(256), 0, stream>>>(msg_src, lastpos);
    k_compact<<<dim3((NN + 255) / 256), dim3(256), 0, stream>>>(lastpos, inv, comp, count);
    k_cvtw<<<dim3(320), dim3(256), 0, stream>>>(W1, W2, gWi, gWh, Wq, Wv, Wo, mW1, mW2, Wk, Hpool);
    k_stage1<<<dim3((MM + 63) / 64), dim3(512), 0, stream>>>(
        comp, count, lastpos, msg_dst, msg_eidx, msg_t, last_update,
        memory, edge_feats, time_w, time_b,
        W1h, b1, W2h, b2, Wih, Whh, gbi, gbh, new_mem);
    k_feat<<<dim3(NN * 16 / 256), dim3(256), 0, stream>>>(
        inv, new_mem, memory, node_feats, feat);

    k2a<<<dim3(Q3 / 32), dim3(256), 0, stream>>>(
        src_nodes, dst_nodes, neg_nodes, feat, time_b, qin_ctx, acat);
    k_gemm<256, 4, false><<<dim3(Q3 / 32, 1), dim3(256), 0, stream>>>(
        qin_ctx, 256, 0, Wqh, 0, bq, 0, q_hm, 256, 0, nullptr, nullptr);
    k_gemm<128, 6, false><<<dim3(Q3 / 32, 2), dim3(256), 0, stream>>>(
        q_hm, 256, 128, Wkth, 384 * 128, nullptr, 0, qk_ws, 768, 384, nullptr, nullptr);
    k2d<<<dim3(Q3 / 4), dim3(256), 0, stream>>>(
        neighbors, nb_eidx, nb_et, edge_times, feat,
        edge_feats, time_w, time_b, bk, q_hm, qk_ws, allm);
    k_gemm<384, 2, false><<<dim3(Q3 / 32, 2), dim3(256), 0, stream>>>(
        qk_ws, 768, 384, Wvh, 128 * 384, bv, 128, qin_ctx, 256, 128, nullptr, nullptr);
    k_gemm<256, 4, false><<<dim3(Q3 / 32, 1), dim3(256), 0, stream>>>(
        qin_ctx, 256, 0, Woh, 0, bo, 0, acat, 384, 0, nullptr, allm);
    k_gemm<384, 2, true><<<dim3(Q3 / 32, 1), dim3(256), 0, stream>>>(
        acat, 384, 0, mW1h, 0, mb1, 0, q_hm, 128, 0, nullptr, nullptr);
    k_gemm<128, 2, false><<<dim3(Q3 / 32, 1), dim3(256), 0, stream>>>(
        q_hm, 128, 0, mW2h, 0, mb2, 0, nullptr, 128, 0, out, nullptr);
}